// Round 2
// baseline (1121.006 us; speedup 1.0000x reference)
//
#include <hip/hip_runtime.h>
#include <stdint.h>

typedef float  f32x4 __attribute__((ext_vector_type(4)));
typedef short  s16x8 __attribute__((ext_vector_type(8)));
typedef unsigned short u16x4 __attribute__((ext_vector_type(4)));

#define DEV __device__ __forceinline__

DEV unsigned short f2bf(float f) {
  union { float f; unsigned int u; } v; v.f = f;
  unsigned int u = v.u;
  return (unsigned short)((u + 0x7fffu + ((u >> 16) & 1u)) >> 16);
}
DEV float bf2f(unsigned short h) {
  union { unsigned int u; float f; } v; v.u = ((unsigned int)h) << 16;
  return v.f;
}

typedef const __attribute__((address_space(1))) void* as1cvp;
typedef __attribute__((address_space(3))) void* as3vp;
DEV void gload16(const void* g, void* l) {
  __builtin_amdgcn_global_load_lds((as1cvp)g, (as3vp)l, 16, 0, 0);
}

// ---------------- pack kernels (memory-bound) ----------------

// fp32 [rows][2048] -> bf16 [rows][4096] as [hi | lo]
__global__ __launch_bounds__(256) void pack_hilo(const float* __restrict__ in,
                                                 unsigned short* __restrict__ out, int rows)
{
  const long total = (long)rows * 256;   // groups of 8 cols
  for (long t = (long)blockIdx.x * 256 + threadIdx.x; t < total;
       t += (long)gridDim.x * 256) {
    const long r = t >> 8;
    const int  c = (int)(t & 255) * 8;
    const float* src = in + (r << 11) + c;
    f32x4 x0 = *(const f32x4*)src;
    f32x4 x1 = *(const f32x4*)(src + 4);
    s16x8 h8, l8;
    #pragma unroll
    for (int e = 0; e < 4; ++e) {
      unsigned short h0 = f2bf(x0[e]);
      unsigned short h1 = f2bf(x1[e]);
      h8[e]     = (short)h0;
      h8[e + 4] = (short)h1;
      l8[e]     = (short)f2bf(x0[e] - bf2f(h0));
      l8[e + 4] = (short)f2bf(x1[e] - bf2f(h1));
    }
    unsigned short* drow = out + (r << 12);
    *(s16x8*)(drow + c)        = h8;
    *(s16x8*)(drow + 2048 + c) = l8;
  }
}

// fp32 -> bf16 flat (total8 = count/8)
__global__ __launch_bounds__(256) void pack_bf16(const float* __restrict__ in,
                                                 unsigned short* __restrict__ out, long total8)
{
  for (long t = (long)blockIdx.x * 256 + threadIdx.x; t < total8;
       t += (long)gridDim.x * 256) {
    const float* src = in + t * 8;
    f32x4 x0 = *(const f32x4*)src;
    f32x4 x1 = *(const f32x4*)(src + 4);
    s16x8 h8;
    #pragma unroll
    for (int e = 0; e < 4; ++e) {
      h8[e]     = (short)f2bf(x0[e]);
      h8[e + 4] = (short)f2bf(x1[e]);
    }
    *(s16x8*)(out + t * 8) = h8;
  }
}

// ---------------- fast bf16 NT GEMM (m97 structure) ----------------
// C[m,n] = sum_k A[m,k]*B[n,k] (+bias[n]); A,B bf16 K-contiguous.
// NSLICE==3: logical K = 6144 over physical [hi|lo] (stride 4096):
//   slice 0: Ah*Bh   slice 1: Al*Bh   slice 2: Ah*Bl
// OM: 0 = fp32 row-major (+bias); 1 = bf16 scatter vT[((b*8+h)*256+i)*256+s];
//     2 = bf16 row-major batched (agg output layout)
template<int NSLICE, int OM, bool BATCHED>
__global__ __launch_bounds__(256)
void fgemm(const unsigned short* __restrict__ A, const unsigned short* __restrict__ B,
           const float* __restrict__ bias, void* __restrict__ C,
           int lda, int ldb, int ldc, int KT)
{
  __shared__ __align__(16) unsigned short lA[128 * 32];
  __shared__ __align__(16) unsigned short lB[128 * 32];

  const int tid  = threadIdx.x;
  const int lane = tid & 63;
  const int wid  = tid >> 6;
  const int wr   = wid >> 1;
  const int wc   = wid & 1;

  const int z  = BATCHED ? blockIdx.z : 0;
  const int m0 = blockIdx.y * 128;
  const int n0 = blockIdx.x * 128;

  long aBase = (long)m0 * lda;
  long bBase = (long)n0 * ldb;
  if (BATCHED) {
    aBase += (long)z * 256 * lda;
    bBase += (long)z * 256 * ldb;
  }

  // staging chunks: g in [0,512), 16B each; row = g>>2, col8 = (g&3)*8
  const int g0 = tid, g1 = tid + 256;
  const int ar0 = g0 >> 2, ac0 = (g0 & 3) * 8;
  const int ar1 = g1 >> 2, ac1 = (g1 & 3) * 8;

  f32x4 acc[4][4];
  #pragma unroll
  for (int i = 0; i < 4; ++i)
    #pragma unroll
    for (int j = 0; j < 4; ++j)
      acc[i][j] = (f32x4)(0.0f);

  const int fr   = lane & 15;
  const int krow = (lane >> 4) * 8;

  for (int kt = 0; kt < KT; kt += 32) {
    int acol, bcol;
    if (NSLICE == 3) {
      const int sl = kt >> 11;
      const int w  = kt & 2047;
      acol = w + ((sl == 1) ? 2048 : 0);
      bcol = w + ((sl == 2) ? 2048 : 0);
    } else {
      acol = kt; bcol = kt;
    }
    gload16(A + aBase + (long)ar0 * lda + acol + ac0, lA + g0 * 8);
    gload16(A + aBase + (long)ar1 * lda + acol + ac1, lA + g1 * 8);
    gload16(B + bBase + (long)ar0 * ldb + bcol + ac0, lB + g0 * 8);
    gload16(B + bBase + (long)ar1 * ldb + bcol + ac1, lB + g1 * 8);
    __syncthreads();   // drains vmcnt -> LDS tiles ready

    s16x8 a0[4], b0[4];
    #pragma unroll
    for (int i = 0; i < 4; ++i)
      a0[i] = *(const s16x8*)&lA[(wr * 64 + i * 16 + fr) * 32 + krow];
    #pragma unroll
    for (int j = 0; j < 4; ++j)
      b0[j] = *(const s16x8*)&lB[(wc * 64 + j * 16 + fr) * 32 + krow];

    #pragma unroll
    for (int i = 0; i < 4; ++i)
      #pragma unroll
      for (int j = 0; j < 4; ++j)
        acc[i][j] = __builtin_amdgcn_mfma_f32_16x16x32_bf16(a0[i], b0[j], acc[i][j], 0, 0, 0);

    __syncthreads();   // all waves done reading before next stage
  }

  // Epilogue. C/D frag: col = lane&15, row = (lane>>4)*4 + reg  [m89-verified]
  const int rg = (lane >> 4) * 4;
  #pragma unroll
  for (int j = 0; j < 4; ++j) {
    const int gn = n0 + wc * 64 + j * 16 + fr;
    const float bvl = bias ? bias[gn] : 0.0f;
    #pragma unroll
    for (int i = 0; i < 4; ++i) {
      const int gmB = m0 + wr * 64 + i * 16 + rg;
      f32x4 v = acc[i][j];
      if (OM == 0) {
        float* Cf = (float*)C;
        #pragma unroll
        for (int r = 0; r < 4; ++r)
          Cf[(long)(gmB + r) * ldc + gn] = v[r] + bvl;
      } else if (OM == 2) {
        long cb = 0;
        if (BATCHED) cb = (long)(z >> 3) * 256 * ldc + (long)(z & 7) * 256;
        unsigned short* Ch = (unsigned short*)C;
        #pragma unroll
        for (int r = 0; r < 4; ++r)
          Ch[cb + (long)(gmB + r) * ldc + gn] = f2bf(v[r] + bvl);
      } else { // OM == 1: vT[((b*8+h)*256 + i)*256 + s], 4 consecutive s -> one 8B store
        const int b = gmB >> 8, s = gmB & 255, h = gn >> 8, ii = gn & 255;
        u16x4 o;
        #pragma unroll
        for (int r = 0; r < 4; ++r) o[r] = f2bf(v[r] + bvl);
        *(u16x4*)&((unsigned short*)C)[((long)((b * 8 + h) * 256 + ii) << 8) + s] = o;
      }
    }
  }
}

// ---------------- circular correlation + softmax ----------------
// one wave per (b,h,l) row; kproj split across two buffers (b<16 / b>=16)
__global__ __launch_bounds__(256)
void corr_softmax(const float* __restrict__ qp, const float* __restrict__ kp0,
                  const float* __restrict__ kp1, const float* __restrict__ temp,
                  unsigned short* __restrict__ w)
{
  __shared__ float qs[4][520];
  __shared__ float ks[4][264];
  const int tid  = threadIdx.x;
  const int lane = tid & 63;
  const int wid  = tid >> 6;
  const int row  = blockIdx.x * 4 + wid;       // ((b*8+h)*256+l)
  const int b = row >> 11;
  const int h = (row >> 8) & 7;
  const int l = row & 255;
  const long qbase = ((long)(b * 256 + l) << 11) + h * 256;
  const float* kb  = (b < 16) ? kp0 : kp1;
  const long kbase = ((long)((b & 15) * 256 + l) << 11) + h * 256;

  {
    f32x4 qv = *(const f32x4*)(qp + qbase + 4 * lane);
    f32x4 kv = *(const f32x4*)(kb + kbase + 4 * lane);
    *(f32x4*)&qs[wid][4 * lane]       = qv;
    *(f32x4*)&qs[wid][256 + 4 * lane] = qv;
    *(f32x4*)&ks[wid][4 * lane]       = kv;
  }
  __syncthreads();

  float c0 = 0.f, c1 = 0.f, c2 = 0.f, c3 = 0.f;
  const int d = 4 * lane;
  const float* Q  = &qs[wid][0];
  const float* Kv = &ks[wid][0];
  #pragma unroll 4
  for (int u0 = 0; u0 < 256; u0 += 4) {
    f32x4 K4 = *(const f32x4*)(Kv + u0);
    f32x4 Qa = *(const f32x4*)(Q + u0 + d);
    f32x4 Qb = *(const f32x4*)(Q + u0 + d + 4);
    c0 += K4[0]*Qa[0] + K4[1]*Qa[1] + K4[2]*Qa[2] + K4[3]*Qa[3];
    c1 += K4[0]*Qa[1] + K4[1]*Qa[2] + K4[2]*Qa[3] + K4[3]*Qb[0];
    c2 += K4[0]*Qa[2] + K4[1]*Qa[3] + K4[2]*Qb[0] + K4[3]*Qb[1];
    c3 += K4[0]*Qa[3] + K4[1]*Qb[0] + K4[2]*Qb[1] + K4[3]*Qb[2];
  }

  const float invT = 1.0f / temp[h];
  float mx = fmaxf(fmaxf(c0, c1), fmaxf(c2, c3));
  #pragma unroll
  for (int off = 32; off >= 1; off >>= 1) mx = fmaxf(mx, __shfl_xor(mx, off, 64));
  const float e0 = __expf((c0 - mx) * invT);
  const float e1 = __expf((c1 - mx) * invT);
  const float e2 = __expf((c2 - mx) * invT);
  const float e3 = __expf((c3 - mx) * invT);
  float sm = e0 + e1 + e2 + e3;
  #pragma unroll
  for (int off = 32; off >= 1; off >>= 1) sm += __shfl_xor(sm, off, 64);
  const float rs = 1.0f / sm;
  u16x4 o;
  o[0] = f2bf(e0 * rs); o[1] = f2bf(e1 * rs); o[2] = f2bf(e2 * rs); o[3] = f2bf(e3 * rs);
  *(u16x4*)(w + (long)row * 256 + d) = o;
}

// ---------------- launcher ----------------

extern "C" void kernel_launch(void* const* d_in, const int* in_sizes, int n_in,
                              void* d_out, int out_size, void* d_ws, size_t ws_size,
                              hipStream_t stream) {
  (void)in_sizes; (void)n_in; (void)out_size; (void)ws_size;
  const float* queries = (const float*)d_in[0];
  const float* keys    = (const float*)d_in[1];
  const float* values  = (const float*)d_in[2];
  const float* Wq = (const float*)d_in[3];
  const float* bq = (const float*)d_in[4];
  const float* Wk = (const float*)d_in[5];
  const float* bk = (const float*)d_in[6];
  const float* Wv = (const float*)d_in[7];
  const float* bv = (const float*)d_in[8];
  const float* Wo = (const float*)d_in[9];
  const float* bo = (const float*)d_in[10];
  const float* temp = (const float*)d_in[11];

  // workspace layout, peak 176 MiB (lifetimes carefully ordered):
  //  kproj0 [0,32)   vT [0,32)       (vT after corr)
  //  qproj  [32,96)  out2 [32,64), Wob [64,72)   (after corr)
  //  extw   [96,112) wgt [96,128)    (wgt after K GEMMs)
  //  ext    [112,176) for Q (full); exth [112,144) for K chunks
  //  kproj1 [144,176)
  //  Vb [128,160), Wvb [160,168)     (after corr)
  char* ws = (char*)d_ws;
  auto MB = [](size_t m) { return m << 20; };
  unsigned short* kproj0u = (unsigned short*)(ws + 0);          // as fp32 below
  float* kproj0 = (float*)(ws + 0);
  float* qproj  = (float*)(ws + MB(32));
  unsigned short* extw = (unsigned short*)(ws + MB(96));
  unsigned short* ext  = (unsigned short*)(ws + MB(112));
  unsigned short* exth = (unsigned short*)(ws + MB(112));
  float* kproj1 = (float*)(ws + MB(144));
  unsigned short* wgt  = (unsigned short*)(ws + MB(96));
  unsigned short* Vb   = (unsigned short*)(ws + MB(128));
  unsigned short* Wvb  = (unsigned short*)(ws + MB(160));
  unsigned short* vTb  = (unsigned short*)(ws + 0);
  unsigned short* out2 = (unsigned short*)(ws + MB(32));
  unsigned short* Wob  = (unsigned short*)(ws + MB(64));
  (void)kproj0u;

  dim3 blk(256);

  // ---- Q projection (full M = 8192), triple via K=6144 slice-mapped GEMM ----
  pack_hilo<<<2048, blk, 0, stream>>>(Wq, extw, 2048);
  pack_hilo<<<2048, blk, 0, stream>>>(queries, ext, 8192);
  fgemm<3, 0, false><<<dim3(16, 64), blk, 0, stream>>>(ext, extw, bq, qproj,
                                                       4096, 4096, 2048, 6144);
  // ---- K projection (2 chunks of M = 4096) ----
  pack_hilo<<<2048, blk, 0, stream>>>(Wk, extw, 2048);
  pack_hilo<<<2048, blk, 0, stream>>>(keys, exth, 4096);
  fgemm<3, 0, false><<<dim3(16, 32), blk, 0, stream>>>(exth, extw, bk, kproj0,
                                                       4096, 4096, 2048, 6144);
  pack_hilo<<<2048, blk, 0, stream>>>(keys + (long)4096 * 2048, exth, 4096);
  fgemm<3, 0, false><<<dim3(16, 32), blk, 0, stream>>>(exth, extw, bk, kproj1,
                                                       4096, 4096, 2048, 6144);
  // ---- correlation + softmax ----
  corr_softmax<<<dim3(16384), blk, 0, stream>>>(qproj, kproj0, kproj1, temp, wgt);
  // ---- V projection (bf16), epilogue scatters transposed vT[b,h,i,s] ----
  pack_bf16<<<2048, blk, 0, stream>>>(values, Vb, (long)8192 * 2048 / 8);
  pack_bf16<<<2048, blk, 0, stream>>>(Wv, Wvb, (long)2048 * 2048 / 8);
  fgemm<1, 1, false><<<dim3(16, 64), blk, 0, stream>>>(Vb, Wvb, bv, vTb,
                                                       2048, 2048, 0, 2048);
  // ---- aggregation: out2[b*256+l][h*256+i] = sum_s wgt[bhl][s]*vT[bhi][s] ----
  fgemm<1, 2, true><<<dim3(2, 2, 256), blk, 0, stream>>>(wgt, vTb, nullptr, out2,
                                                         256, 256, 2048, 256);
  // ---- O projection -> d_out (fp32) ----
  pack_bf16<<<2048, blk, 0, stream>>>(Wo, Wob, (long)2048 * 2048 / 8);
  fgemm<1, 0, false><<<dim3(16, 64), blk, 0, stream>>>(out2, Wob, bo, (float*)d_out,
                                                       2048, 2048, 2048, 2048);
}

// Round 3
// 873.950 us; speedup vs baseline: 1.2827x; 1.2827x over previous
//
#include <hip/hip_runtime.h>
#include <stdint.h>

typedef float  f32x4 __attribute__((ext_vector_type(4)));
typedef short  s16x8 __attribute__((ext_vector_type(8)));
typedef unsigned short u16x4 __attribute__((ext_vector_type(4)));

#define DEV __device__ __forceinline__

DEV unsigned short f2bf(float f) {
  union { float f; unsigned int u; } v; v.f = f;
  unsigned int u = v.u;
  return (unsigned short)((u + 0x7fffu + ((u >> 16) & 1u)) >> 16);
}
DEV float bf2f(unsigned short h) {
  union { unsigned int u; float f; } v; v.u = ((unsigned int)h) << 16;
  return v.f;
}

typedef const __attribute__((address_space(1))) void* as1cvp;
typedef __attribute__((address_space(3))) void* as3vp;
DEV void gload16(const void* g, void* l) {
  __builtin_amdgcn_global_load_lds((as1cvp)g, (as3vp)l, 16, 0, 0);
}

// ---------------- pack kernels (memory-bound) ----------------

// fp32 [rows][2048] -> bf16 [rows][4096] as [hi | lo]
__global__ __launch_bounds__(256) void pack_hilo(const float* __restrict__ in,
                                                 unsigned short* __restrict__ out, int rows)
{
  const long total = (long)rows * 256;   // groups of 8 cols
  for (long t = (long)blockIdx.x * 256 + threadIdx.x; t < total;
       t += (long)gridDim.x * 256) {
    const long r = t >> 8;
    const int  c = (int)(t & 255) * 8;
    const float* src = in + (r << 11) + c;
    f32x4 x0 = *(const f32x4*)src;
    f32x4 x1 = *(const f32x4*)(src + 4);
    s16x8 h8, l8;
    #pragma unroll
    for (int e = 0; e < 4; ++e) {
      unsigned short h0 = f2bf(x0[e]);
      unsigned short h1 = f2bf(x1[e]);
      h8[e]     = (short)h0;
      h8[e + 4] = (short)h1;
      l8[e]     = (short)f2bf(x0[e] - bf2f(h0));
      l8[e + 4] = (short)f2bf(x1[e] - bf2f(h1));
    }
    unsigned short* drow = out + (r << 12);
    *(s16x8*)(drow + c)        = h8;
    *(s16x8*)(drow + 2048 + c) = l8;
  }
}

// fp32 -> bf16 flat (total8 = count/8)
__global__ __launch_bounds__(256) void pack_bf16(const float* __restrict__ in,
                                                 unsigned short* __restrict__ out, long total8)
{
  for (long t = (long)blockIdx.x * 256 + threadIdx.x; t < total8;
       t += (long)gridDim.x * 256) {
    const float* src = in + t * 8;
    f32x4 x0 = *(const f32x4*)src;
    f32x4 x1 = *(const f32x4*)(src + 4);
    s16x8 h8;
    #pragma unroll
    for (int e = 0; e < 4; ++e) {
      h8[e]     = (short)f2bf(x0[e]);
      h8[e + 4] = (short)f2bf(x1[e]);
    }
    *(s16x8*)(out + t * 8) = h8;
  }
}

// ---------------- bf16 NT GEMM, combined dual-subtile staging ----------------
// C[m,n] = sum_k A[m,k]*B[n,k] (+bias[n]); A,B bf16 K-contiguous.
// Per K-step stage TWO 128x32 subtiles per matrix (32 KB), then:
//   MODE 0 (triple): subtiles = {hi(kt), lo(kt)} planes (lo at col+2048);
//                    48 MFMA: AhBh + AhBl + AlBh; kt += 32 over hi-plane K.
//   MODE 1 (plain2): subtiles = {kt, kt+32}; 32 MFMA; kt += 64.
// OM: 0 = fp32 row-major (+bias); 1 = bf16 scatter vT[((b*8+h)*256+i)*256+s];
//     2 = bf16 row-major batched (agg output layout)
template<int MODE, int OM, bool BATCHED>
__global__ __launch_bounds__(256)
void fgemm(const unsigned short* __restrict__ A, const unsigned short* __restrict__ B,
           const float* __restrict__ bias, void* __restrict__ C,
           int lda, int ldb, int ldc, int KT)
{
  __shared__ __align__(16) unsigned short lA[2 * 128 * 32];
  __shared__ __align__(16) unsigned short lB[2 * 128 * 32];

  const int tid  = threadIdx.x;
  const int lane = tid & 63;
  const int wid  = tid >> 6;
  const int wr   = wid >> 1;
  const int wc   = wid & 1;

  const int z  = BATCHED ? blockIdx.z : 0;
  const int m0 = blockIdx.y * 128;
  const int n0 = blockIdx.x * 128;

  long aBase = (long)m0 * lda;
  long bBase = (long)n0 * ldb;
  if (BATCHED) {
    aBase += (long)z * 256 * lda;
    bBase += (long)z * 256 * ldb;
  }

  // staging: one 128x32 subtile = 512 x 16B chunks; thread t covers chunks {t, t+256}
  const int ar0 = tid >> 2, ac0 = (tid & 3) * 8;          // chunk t
  const int ar1 = ar0 + 64, ac1 = ac0;                    // chunk t+256

  const unsigned short* pa0 = A + aBase + (long)ar0 * lda + ac0;
  const unsigned short* pa1 = A + aBase + (long)ar1 * lda + ac1;
  const unsigned short* pb0 = B + bBase + (long)ar0 * ldb + ac0;
  const unsigned short* pb1 = B + bBase + (long)ar1 * ldb + ac1;

  constexpr int SUBOFF = (MODE == 0) ? 2048 : 32;  // second-subtile column offset
  constexpr int KSTEP  = (MODE == 0) ? 32 : 64;

  f32x4 acc[4][4];
  #pragma unroll
  for (int i = 0; i < 4; ++i)
    #pragma unroll
    for (int j = 0; j < 4; ++j)
      acc[i][j] = (f32x4)(0.0f);

  const int fr   = lane & 15;
  const int krow = (lane >> 4) * 8;

  for (int kt = 0; kt < KT; kt += KSTEP) {
    gload16(pa0 + kt,          lA + tid * 8);
    gload16(pa1 + kt,          lA + (tid + 256) * 8);
    gload16(pa0 + kt + SUBOFF, lA + 4096 + tid * 8);
    gload16(pa1 + kt + SUBOFF, lA + 4096 + (tid + 256) * 8);
    gload16(pb0 + kt,          lB + tid * 8);
    gload16(pb1 + kt,          lB + (tid + 256) * 8);
    gload16(pb0 + kt + SUBOFF, lB + 4096 + tid * 8);
    gload16(pb1 + kt + SUBOFF, lB + 4096 + (tid + 256) * 8);
    __syncthreads();   // drains vmcnt -> LDS subtiles ready

    s16x8 a0[4], a1[4], b0[4], b1[4];
    #pragma unroll
    for (int i = 0; i < 4; ++i) {
      const int r = (wr * 64 + i * 16 + fr) * 32 + krow;
      a0[i] = *(const s16x8*)&lA[r];
      a1[i] = *(const s16x8*)&lA[4096 + r];
    }
    #pragma unroll
    for (int j = 0; j < 4; ++j) {
      const int r = (wc * 64 + j * 16 + fr) * 32 + krow;
      b0[j] = *(const s16x8*)&lB[r];
      b1[j] = *(const s16x8*)&lB[4096 + r];
    }

    #pragma unroll
    for (int i = 0; i < 4; ++i)
      #pragma unroll
      for (int j = 0; j < 4; ++j) {
        if (MODE == 0) {
          acc[i][j] = __builtin_amdgcn_mfma_f32_16x16x32_bf16(a1[i], b0[j], acc[i][j], 0, 0, 0);
          acc[i][j] = __builtin_amdgcn_mfma_f32_16x16x32_bf16(a0[i], b1[j], acc[i][j], 0, 0, 0);
          acc[i][j] = __builtin_amdgcn_mfma_f32_16x16x32_bf16(a0[i], b0[j], acc[i][j], 0, 0, 0);
        } else {
          acc[i][j] = __builtin_amdgcn_mfma_f32_16x16x32_bf16(a0[i], b0[j], acc[i][j], 0, 0, 0);
          acc[i][j] = __builtin_amdgcn_mfma_f32_16x16x32_bf16(a1[i], b1[j], acc[i][j], 0, 0, 0);
        }
      }

    __syncthreads();   // all waves done reading before next stage
  }

  // Epilogue. C/D frag: col = lane&15, row = (lane>>4)*4 + reg  [m89-verified]
  const int rg = (lane >> 4) * 4;
  #pragma unroll
  for (int j = 0; j < 4; ++j) {
    const int gn = n0 + wc * 64 + j * 16 + fr;
    const float bvl = bias ? bias[gn] : 0.0f;
    #pragma unroll
    for (int i = 0; i < 4; ++i) {
      const int gmB = m0 + wr * 64 + i * 16 + rg;
      f32x4 v = acc[i][j];
      if (OM == 0) {
        float* Cf = (float*)C;
        #pragma unroll
        for (int r = 0; r < 4; ++r)
          Cf[(long)(gmB + r) * ldc + gn] = v[r] + bvl;
      } else if (OM == 2) {
        long cb = 0;
        if (BATCHED) cb = (long)(z >> 3) * 256 * ldc + (long)(z & 7) * 256;
        unsigned short* Ch = (unsigned short*)C;
        #pragma unroll
        for (int r = 0; r < 4; ++r)
          Ch[cb + (long)(gmB + r) * ldc + gn] = f2bf(v[r] + bvl);
      } else { // OM == 1: vT[((b*8+h)*256 + i)*256 + s], 4 consecutive s -> one 8B store
        const int b = gmB >> 8, s = gmB & 255, h = gn >> 8, ii = gn & 255;
        u16x4 o;
        #pragma unroll
        for (int r = 0; r < 4; ++r) o[r] = f2bf(v[r] + bvl);
        *(u16x4*)&((unsigned short*)C)[((long)((b * 8 + h) * 256 + ii) << 8) + s] = o;
      }
    }
  }
}

// ---------------- circular correlation + softmax ----------------
// one wave per (b,h,l) row; kproj split across two buffers (b<16 / b>=16)
__global__ __launch_bounds__(256)
void corr_softmax(const float* __restrict__ qp, const float* __restrict__ kp0,
                  const float* __restrict__ kp1, const float* __restrict__ temp,
                  unsigned short* __restrict__ w)
{
  __shared__ float qs[4][520];
  __shared__ float ks[4][264];
  const int tid  = threadIdx.x;
  const int lane = tid & 63;
  const int wid  = tid >> 6;
  const int row  = blockIdx.x * 4 + wid;       // ((b*8+h)*256+l)
  const int b = row >> 11;
  const int h = (row >> 8) & 7;
  const int l = row & 255;
  const long qbase = ((long)(b * 256 + l) << 11) + h * 256;
  const float* kb  = (b < 16) ? kp0 : kp1;
  const long kbase = ((long)((b & 15) * 256 + l) << 11) + h * 256;

  {
    f32x4 qv = *(const f32x4*)(qp + qbase + 4 * lane);
    f32x4 kv = *(const f32x4*)(kb + kbase + 4 * lane);
    *(f32x4*)&qs[wid][4 * lane]       = qv;
    *(f32x4*)&qs[wid][256 + 4 * lane] = qv;
    *(f32x4*)&ks[wid][4 * lane]       = kv;
  }
  __syncthreads();

  float c0 = 0.f, c1 = 0.f, c2 = 0.f, c3 = 0.f;
  const int d = 4 * lane;
  const float* Q  = &qs[wid][0];
  const float* Kv = &ks[wid][0];
  #pragma unroll 4
  for (int u0 = 0; u0 < 256; u0 += 4) {
    f32x4 K4 = *(const f32x4*)(Kv + u0);
    f32x4 Qa = *(const f32x4*)(Q + u0 + d);
    f32x4 Qb = *(const f32x4*)(Q + u0 + d + 4);
    c0 += K4[0]*Qa[0] + K4[1]*Qa[1] + K4[2]*Qa[2] + K4[3]*Qa[3];
    c1 += K4[0]*Qa[1] + K4[1]*Qa[2] + K4[2]*Qa[3] + K4[3]*Qb[0];
    c2 += K4[0]*Qa[2] + K4[1]*Qa[3] + K4[2]*Qb[0] + K4[3]*Qb[1];
    c3 += K4[0]*Qa[3] + K4[1]*Qb[0] + K4[2]*Qb[1] + K4[3]*Qb[2];
  }

  const float invT = 1.0f / temp[h];
  float mx = fmaxf(fmaxf(c0, c1), fmaxf(c2, c3));
  #pragma unroll
  for (int off = 32; off >= 1; off >>= 1) mx = fmaxf(mx, __shfl_xor(mx, off, 64));
  const float e0 = __expf((c0 - mx) * invT);
  const float e1 = __expf((c1 - mx) * invT);
  const float e2 = __expf((c2 - mx) * invT);
  const float e3 = __expf((c3 - mx) * invT);
  float sm = e0 + e1 + e2 + e3;
  #pragma unroll
  for (int off = 32; off >= 1; off >>= 1) sm += __shfl_xor(sm, off, 64);
  const float rs = 1.0f / sm;
  u16x4 o;
  o[0] = f2bf(e0 * rs); o[1] = f2bf(e1 * rs); o[2] = f2bf(e2 * rs); o[3] = f2bf(e3 * rs);
  *(u16x4*)(w + (long)row * 256 + d) = o;
}

// ---------------- launcher ----------------

extern "C" void kernel_launch(void* const* d_in, const int* in_sizes, int n_in,
                              void* d_out, int out_size, void* d_ws, size_t ws_size,
                              hipStream_t stream) {
  (void)in_sizes; (void)n_in; (void)out_size; (void)ws_size;
  const float* queries = (const float*)d_in[0];
  const float* keys    = (const float*)d_in[1];
  const float* values  = (const float*)d_in[2];
  const float* Wq = (const float*)d_in[3];
  const float* bq = (const float*)d_in[4];
  const float* Wk = (const float*)d_in[5];
  const float* bk = (const float*)d_in[6];
  const float* Wv = (const float*)d_in[7];
  const float* bv = (const float*)d_in[8];
  const float* Wo = (const float*)d_in[9];
  const float* bo = (const float*)d_in[10];
  const float* temp = (const float*)d_in[11];

  // workspace layout, peak 176 MiB (lifetimes carefully ordered):
  //  kproj0 [0,32)   vT [0,32)       (vT after corr)
  //  qproj  [32,96)  out2 [32,64), Wob [64,72)   (after corr)
  //  extw   [96,112) wgt [96,128)    (wgt after K GEMMs)
  //  ext    [112,176) for Q (full); exth [112,144) for K chunks
  //  kproj1 [144,176)
  //  Vb [128,160), Wvb [160,168)     (after corr)
  char* ws = (char*)d_ws;
  auto MB = [](size_t m) { return m << 20; };
  float* kproj0 = (float*)(ws + 0);
  float* qproj  = (float*)(ws + MB(32));
  unsigned short* extw = (unsigned short*)(ws + MB(96));
  unsigned short* ext  = (unsigned short*)(ws + MB(112));
  unsigned short* exth = (unsigned short*)(ws + MB(112));
  float* kproj1 = (float*)(ws + MB(144));
  unsigned short* wgt  = (unsigned short*)(ws + MB(96));
  unsigned short* Vb   = (unsigned short*)(ws + MB(128));
  unsigned short* Wvb  = (unsigned short*)(ws + MB(160));
  unsigned short* vTb  = (unsigned short*)(ws + 0);
  unsigned short* out2 = (unsigned short*)(ws + MB(32));
  unsigned short* Wob  = (unsigned short*)(ws + MB(64));

  dim3 blk(256);

  // ---- Q projection (full M = 8192), triple with combined hi/lo staging ----
  pack_hilo<<<2048, blk, 0, stream>>>(Wq, extw, 2048);
  pack_hilo<<<2048, blk, 0, stream>>>(queries, ext, 8192);
  fgemm<0, 0, false><<<dim3(16, 64), blk, 0, stream>>>(ext, extw, bq, qproj,
                                                       4096, 4096, 2048, 2048);
  // ---- K projection (2 chunks of M = 4096) ----
  pack_hilo<<<2048, blk, 0, stream>>>(Wk, extw, 2048);
  pack_hilo<<<2048, blk, 0, stream>>>(keys, exth, 4096);
  fgemm<0, 0, false><<<dim3(16, 32), blk, 0, stream>>>(exth, extw, bk, kproj0,
                                                       4096, 4096, 2048, 2048);
  pack_hilo<<<2048, blk, 0, stream>>>(keys + (long)4096 * 2048, exth, 4096);
  fgemm<0, 0, false><<<dim3(16, 32), blk, 0, stream>>>(exth, extw, bk, kproj1,
                                                       4096, 4096, 2048, 2048);
  // ---- correlation + softmax ----
  corr_softmax<<<dim3(16384), blk, 0, stream>>>(qproj, kproj0, kproj1, temp, wgt);
  // ---- V projection (bf16), epilogue scatters transposed vT[b,h,i,s] ----
  pack_bf16<<<2048, blk, 0, stream>>>(values, Vb, (long)8192 * 2048 / 8);
  pack_bf16<<<2048, blk, 0, stream>>>(Wv, Wvb, (long)2048 * 2048 / 8);
  fgemm<1, 1, false><<<dim3(16, 64), blk, 0, stream>>>(Vb, Wvb, bv, vTb,
                                                       2048, 2048, 0, 2048);
  // ---- aggregation: out2[b*256+l][h*256+i] = sum_s wgt[bhl][s]*vT[bhi][s] ----
  fgemm<1, 2, true><<<dim3(2, 2, 256), blk, 0, stream>>>(wgt, vTb, nullptr, out2,
                                                         256, 256, 2048, 256);
  // ---- O projection -> d_out (fp32) ----
  pack_bf16<<<2048, blk, 0, stream>>>(Wo, Wob, (long)2048 * 2048 / 8);
  fgemm<1, 0, false><<<dim3(16, 64), blk, 0, stream>>>(out2, Wob, bo, (float*)d_out,
                                                       2048, 2048, 2048, 2048);
}

// Round 4
// 785.301 us; speedup vs baseline: 1.4275x; 1.1129x over previous
//
#include <hip/hip_runtime.h>
#include <stdint.h>

typedef float  f32x4 __attribute__((ext_vector_type(4)));
typedef short  s16x8 __attribute__((ext_vector_type(8)));
typedef unsigned short u16x4 __attribute__((ext_vector_type(4)));

#define DEV __device__ __forceinline__

DEV unsigned short f2bf(float f) {
  union { float f; unsigned int u; } v; v.f = f;
  unsigned int u = v.u;
  return (unsigned short)((u + 0x7fffu + ((u >> 16) & 1u)) >> 16);
}
DEV float bf2f(unsigned short h) {
  union { unsigned int u; float f; } v; v.u = ((unsigned int)h) << 16;
  return v.f;
}

typedef const __attribute__((address_space(1))) void* as1cvp;
typedef __attribute__((address_space(3))) void* as3vp;
DEV void gload16(const void* g, void* l) {
  __builtin_amdgcn_global_load_lds((as1cvp)g, (as3vp)l, 16, 0, 0);
}

// ---------------- pack kernels (memory-bound) ----------------

// fp32 [rows][2048] -> bf16 [rows][4096] as [hi | lo]
__global__ __launch_bounds__(256) void pack_hilo(const float* __restrict__ in,
                                                 unsigned short* __restrict__ out, int rows)
{
  const long total = (long)rows * 256;
  for (long t = (long)blockIdx.x * 256 + threadIdx.x; t < total;
       t += (long)gridDim.x * 256) {
    const long r = t >> 8;
    const int  c = (int)(t & 255) * 8;
    const float* src = in + (r << 11) + c;
    f32x4 x0 = *(const f32x4*)src;
    f32x4 x1 = *(const f32x4*)(src + 4);
    s16x8 h8, l8;
    #pragma unroll
    for (int e = 0; e < 4; ++e) {
      unsigned short h0 = f2bf(x0[e]);
      unsigned short h1 = f2bf(x1[e]);
      h8[e]     = (short)h0;
      h8[e + 4] = (short)h1;
      l8[e]     = (short)f2bf(x0[e] - bf2f(h0));
      l8[e + 4] = (short)f2bf(x1[e] - bf2f(h1));
    }
    unsigned short* drow = out + (r << 12);
    *(s16x8*)(drow + c)        = h8;
    *(s16x8*)(drow + 2048 + c) = l8;
  }
}

__global__ __launch_bounds__(256) void pack_bf16(const float* __restrict__ in,
                                                 unsigned short* __restrict__ out, long total8)
{
  for (long t = (long)blockIdx.x * 256 + threadIdx.x; t < total8;
       t += (long)gridDim.x * 256) {
    const float* src = in + t * 8;
    f32x4 x0 = *(const f32x4*)src;
    f32x4 x1 = *(const f32x4*)(src + 4);
    s16x8 h8;
    #pragma unroll
    for (int e = 0; e < 4; ++e) {
      h8[e]     = (short)f2bf(x0[e]);
      h8[e + 4] = (short)f2bf(x1[e]);
    }
    *(s16x8*)(out + t * 8) = h8;
  }
}

// ---------------- 256x256 8-phase bf16 NT GEMM ----------------
// M=8192 (grid.y*256), N=2048 (grid.x*256). C[m,n] = sum_k A[m,k]*B[n,k] + bias[n].
// NSLICE 3: logical K=6144 over [hi|lo] planes (stride 4096): AhBh + AlBh + AhBl.
// OM 0: fp32 row-major (ldc 2048); OM 1: bf16 scatter vT[((b*8+h)*256+i)*256+s].
// Schedule (derived from the verified 8-phase template):
//   8 waves (wm=wid>>2, wn=wid&3), per-wave C = 128x64, acc[8][4] f32x4.
//   LDS 128KB: buf d at d*32768u; A halves at +{0,8192}u; B at +16384+{0,8192}u.
//   Swizzle st_16x32: ushort idx u ^= ((u>>8)&1)<<4; staged via pre-swizzled
//   global source col (chunk-col ^ ((tid>>5)&1)<<1), LDS dest linear.
//   Phases P0..P7: stage units {b1A1(t1c), b0B0,b0B1,b0A0(ts0), b0A1(ts0),
//   b1B0,b1B1,b1A0(ts1)}; vmcnt(6) before closing barrier of P3 and P7.
template<int NSLICE, int OM>
__global__ __launch_bounds__(512, 2)
void gemm8p(const unsigned short* __restrict__ Ap, const unsigned short* __restrict__ Bp,
            const float* __restrict__ bias, void* __restrict__ Cp)
{
  constexpr int LDA = (NSLICE == 3) ? 4096 : 2048;
  constexpr int LDB = (NSLICE == 3) ? 4096 : 2048;
  constexpr int LDC = 2048;
  constexpr int NT  = (NSLICE == 3) ? 96 : 32;   // K-tiles of 64
  constexpr int NI  = NT / 2;

  __shared__ __align__(16) unsigned short lds[65536];  // 128 KB

  const int tid  = threadIdx.x;
  const int lane = tid & 63;
  const int wid  = tid >> 6;
  const int wm   = wid >> 2;        // 0..1
  const int wn   = wid & 3;         // 0..3
  const int fr   = lane & 15;
  const int ko   = (lane >> 4) * 8;

  const int m0 = blockIdx.y * 256;
  const int n0 = blockIdx.x * 256;

  // staging constants: chunk = tid (and +512); 8 chunks/row of 64 cols
  const int sr  = tid >> 3;                                   // row 0..63
  const int scc = (((tid & 7) ^ (((tid >> 5) & 1) << 1)) << 3); // src col elems

  auto sA = [&](int d, int u, int col) {
    const unsigned short* s0 = Ap + (long)(m0 + u * 64 + sr) * LDA + col + scc;
    const int lb = d * 32768 + u * 4096 + (wid << 9);
    gload16(s0, lds + lb);
    gload16(s0 + 128 * LDA, lds + lb + 8192);
  };
  auto sB = [&](int d, int h, int col) {
    const unsigned short* s0 = Bp + (long)(n0 + h * 128 + sr) * LDB + col + scc;
    const int lb = d * 32768 + 16384 + h * 8192 + (wid << 9);
    gload16(s0, lds + lb);
    gload16(s0 + 64 * LDB, lds + lb + 4096);
  };
  auto acol = [](int t) -> int {
    if (NSLICE == 3) { int sl = t >> 5, kw = (t & 31) << 6; return kw + (sl == 1 ? 2048 : 0); }
    return t << 6;
  };
  auto bcol = [](int t) -> int {
    if (NSLICE == 3) { int sl = t >> 5, kw = (t & 31) << 6; return kw + (sl == 2 ? 2048 : 0); }
    return t << 6;
  };

  f32x4 acc[8][4];
  #pragma unroll
  for (int i = 0; i < 8; ++i)
    #pragma unroll
    for (int j = 0; j < 4; ++j)
      acc[i][j] = (f32x4)(0.0f);

  s16x8 afr[2][2], bfr[4][2];

#define LOADB(d)                                                              \
  _Pragma("unroll") for (int ni = 0; ni < 4; ++ni)                            \
    _Pragma("unroll") for (int kk = 0; kk < 2; ++kk) {                        \
      const int nr = wn * 64 + ni * 16 + fr;                                  \
      int u = (d) * 32768 + 16384 + (nr >> 7) * 8192 + (nr & 127) * 64        \
              + kk * 32 + ko;                                                 \
      u ^= ((u >> 8) & 1) << 4;                                               \
      bfr[ni][kk] = *(const s16x8*)&lds[u];                                   \
    }

#define PHASE(d, q, DOB, STAGE, VM)                                           \
  {                                                                           \
    if (DOB) { LOADB(d) }                                                     \
    _Pragma("unroll") for (int ai = 0; ai < 2; ++ai)                          \
      _Pragma("unroll") for (int kk = 0; kk < 2; ++kk) {                      \
        int u = (d) * 32768 + wm * 8192 + ((2 * (q) + ai) * 16 + fr) * 64     \
                + kk * 32 + ko;                                               \
        u ^= ((u >> 8) & 1) << 4;                                             \
        afr[ai][kk] = *(const s16x8*)&lds[u];                                 \
      }                                                                       \
    STAGE;                                                                    \
    __builtin_amdgcn_s_barrier();                                             \
    asm volatile("s_waitcnt lgkmcnt(0)" ::: "memory");                        \
    __builtin_amdgcn_sched_barrier(0);                                        \
    __builtin_amdgcn_s_setprio(1);                                            \
    _Pragma("unroll") for (int ai = 0; ai < 2; ++ai)                          \
      _Pragma("unroll") for (int ni = 0; ni < 4; ++ni)                        \
        _Pragma("unroll") for (int kk = 0; kk < 2; ++kk)                      \
          acc[2 * (q) + ai][ni] = __builtin_amdgcn_mfma_f32_16x16x32_bf16(    \
              afr[ai][kk], bfr[ni][kk], acc[2 * (q) + ai][ni], 0, 0, 0);      \
    __builtin_amdgcn_s_setprio(0);                                            \
    if (VM) { asm volatile("s_waitcnt vmcnt(6)" ::: "memory"); }              \
    __builtin_amdgcn_s_barrier();                                             \
  }

  // prologue: stage tile0 fully + tile1 {B0,B1,A0}; wait; barrier
  sB(0, 0, bcol(0)); sB(0, 1, bcol(0));
  sA(0, 0, acol(0)); sA(0, 1, acol(0));
  sB(1, 0, bcol(1)); sB(1, 1, bcol(1));
  sA(1, 0, acol(1));
  asm volatile("s_waitcnt vmcnt(6)" ::: "memory");
  __builtin_amdgcn_s_barrier();

  for (int i = 0; i < NI; ++i) {
    const int t1  = 2 * i + 1;
    const int ts0 = (2 * i + 2 < NT) ? 2 * i + 2 : NT - 1;
    const int ts1 = (2 * i + 3 < NT) ? 2 * i + 3 : NT - 1;
    const int a1c = acol(t1);
    const int as0 = acol(ts0), bs0 = bcol(ts0);
    const int as1 = acol(ts1), bs1 = bcol(ts1);
    PHASE(0, 0, true,  sA(1, 1, a1c), false)
    PHASE(0, 1, false, sB(0, 0, bs0), false)
    PHASE(0, 2, false, sB(0, 1, bs0), false)
    PHASE(0, 3, false, sA(0, 0, as0), true)
    PHASE(1, 0, true,  sA(0, 1, as0), false)
    PHASE(1, 1, false, sB(1, 0, bs1), false)
    PHASE(1, 2, false, sB(1, 1, bs1), false)
    PHASE(1, 3, false, sA(1, 0, as1), true)
  }
#undef PHASE
#undef LOADB

  // epilogue: C/D frag col = lane&15 (N side), row = (lane>>4)*4 + r (M side)
  const int rg = (lane >> 4) * 4;
  #pragma unroll
  for (int ni = 0; ni < 4; ++ni) {
    const int gn = n0 + wn * 64 + ni * 16 + fr;
    const float bvl = bias[gn];
    #pragma unroll
    for (int mi = 0; mi < 8; ++mi) {
      const int gmB = m0 + wm * 128 + mi * 16 + rg;
      f32x4 v = acc[mi][ni];
      if (OM == 0) {
        float* Cf = (float*)Cp;
        #pragma unroll
        for (int r = 0; r < 4; ++r)
          Cf[(long)(gmB + r) * LDC + gn] = v[r] + bvl;
      } else { // OM == 1: vT[((b*8+h)*256 + i)*256 + s]
        const int b = gmB >> 8, s = gmB & 255, h = gn >> 8, ii = gn & 255;
        u16x4 o;
        #pragma unroll
        for (int r = 0; r < 4; ++r) o[r] = f2bf(v[r] + bvl);
        *(u16x4*)&((unsigned short*)Cp)[((long)((b * 8 + h) * 256 + ii) << 8) + s] = o;
      }
    }
  }
}

// ---------------- 128x128 NT GEMM (m97 structure) — used for aggregation ----
template<int MODE, int OM, bool BATCHED>
__global__ __launch_bounds__(256)
void fgemm(const unsigned short* __restrict__ A, const unsigned short* __restrict__ B,
           const float* __restrict__ bias, void* __restrict__ C,
           int lda, int ldb, int ldc, int KT)
{
  __shared__ __align__(16) unsigned short lA[2 * 128 * 32];
  __shared__ __align__(16) unsigned short lB[2 * 128 * 32];

  const int tid  = threadIdx.x;
  const int lane = tid & 63;
  const int wid  = tid >> 6;
  const int wr   = wid >> 1;
  const int wc   = wid & 1;

  const int z  = BATCHED ? blockIdx.z : 0;
  const int m0 = blockIdx.y * 128;
  const int n0 = blockIdx.x * 128;

  long aBase = (long)m0 * lda;
  long bBase = (long)n0 * ldb;
  if (BATCHED) {
    aBase += (long)z * 256 * lda;
    bBase += (long)z * 256 * ldb;
  }

  const int ar0 = tid >> 2, ac0 = (tid & 3) * 8;
  const int ar1 = ar0 + 64, ac1 = ac0;

  const unsigned short* pa0 = A + aBase + (long)ar0 * lda + ac0;
  const unsigned short* pa1 = A + aBase + (long)ar1 * lda + ac1;
  const unsigned short* pb0 = B + bBase + (long)ar0 * ldb + ac0;
  const unsigned short* pb1 = B + bBase + (long)ar1 * ldb + ac1;

  constexpr int SUBOFF = (MODE == 0) ? 2048 : 32;
  constexpr int KSTEP  = (MODE == 0) ? 32 : 64;

  f32x4 acc[4][4];
  #pragma unroll
  for (int i = 0; i < 4; ++i)
    #pragma unroll
    for (int j = 0; j < 4; ++j)
      acc[i][j] = (f32x4)(0.0f);

  const int fr   = lane & 15;
  const int krow = (lane >> 4) * 8;

  for (int kt = 0; kt < KT; kt += KSTEP) {
    gload16(pa0 + kt,          lA + tid * 8);
    gload16(pa1 + kt,          lA + (tid + 256) * 8);
    gload16(pa0 + kt + SUBOFF, lA + 4096 + tid * 8);
    gload16(pa1 + kt + SUBOFF, lA + 4096 + (tid + 256) * 8);
    gload16(pb0 + kt,          lB + tid * 8);
    gload16(pb1 + kt,          lB + (tid + 256) * 8);
    gload16(pb0 + kt + SUBOFF, lB + 4096 + tid * 8);
    gload16(pb1 + kt + SUBOFF, lB + 4096 + (tid + 256) * 8);
    __syncthreads();

    s16x8 a0[4], a1[4], b0[4], b1[4];
    #pragma unroll
    for (int i = 0; i < 4; ++i) {
      const int r = (wr * 64 + i * 16 + fr) * 32 + krow;
      a0[i] = *(const s16x8*)&lA[r];
      a1[i] = *(const s16x8*)&lA[4096 + r];
    }
    #pragma unroll
    for (int j = 0; j < 4; ++j) {
      const int r = (wc * 64 + j * 16 + fr) * 32 + krow;
      b0[j] = *(const s16x8*)&lB[r];
      b1[j] = *(const s16x8*)&lB[4096 + r];
    }

    #pragma unroll
    for (int i = 0; i < 4; ++i)
      #pragma unroll
      for (int j = 0; j < 4; ++j) {
        if (MODE == 0) {
          acc[i][j] = __builtin_amdgcn_mfma_f32_16x16x32_bf16(a1[i], b0[j], acc[i][j], 0, 0, 0);
          acc[i][j] = __builtin_amdgcn_mfma_f32_16x16x32_bf16(a0[i], b1[j], acc[i][j], 0, 0, 0);
          acc[i][j] = __builtin_amdgcn_mfma_f32_16x16x32_bf16(a0[i], b0[j], acc[i][j], 0, 0, 0);
        } else {
          acc[i][j] = __builtin_amdgcn_mfma_f32_16x16x32_bf16(a0[i], b0[j], acc[i][j], 0, 0, 0);
          acc[i][j] = __builtin_amdgcn_mfma_f32_16x16x32_bf16(a1[i], b1[j], acc[i][j], 0, 0, 0);
        }
      }

    __syncthreads();
  }

  const int rg = (lane >> 4) * 4;
  #pragma unroll
  for (int j = 0; j < 4; ++j) {
    const int gn = n0 + wc * 64 + j * 16 + fr;
    const float bvl = bias ? bias[gn] : 0.0f;
    #pragma unroll
    for (int i = 0; i < 4; ++i) {
      const int gmB = m0 + wr * 64 + i * 16 + rg;
      f32x4 v = acc[i][j];
      if (OM == 0) {
        float* Cf = (float*)C;
        #pragma unroll
        for (int r = 0; r < 4; ++r)
          Cf[(long)(gmB + r) * ldc + gn] = v[r] + bvl;
      } else if (OM == 2) {
        long cb = 0;
        if (BATCHED) cb = (long)(z >> 3) * 256 * ldc + (long)(z & 7) * 256;
        unsigned short* Ch = (unsigned short*)C;
        #pragma unroll
        for (int r = 0; r < 4; ++r)
          Ch[cb + (long)(gmB + r) * ldc + gn] = f2bf(v[r] + bvl);
      } else {
        const int b = gmB >> 8, s = gmB & 255, h = gn >> 8, ii = gn & 255;
        u16x4 o;
        #pragma unroll
        for (int r = 0; r < 4; ++r) o[r] = f2bf(v[r] + bvl);
        *(u16x4*)&((unsigned short*)C)[((long)((b * 8 + h) * 256 + ii) << 8) + s] = o;
      }
    }
  }
}

// ---------------- circular correlation + softmax ----------------
__global__ __launch_bounds__(256)
void corr_softmax(const float* __restrict__ qp, const float* __restrict__ kp0,
                  const float* __restrict__ kp1, const float* __restrict__ temp,
                  unsigned short* __restrict__ w)
{
  __shared__ float qs[4][520];
  __shared__ float ks[4][264];
  const int tid  = threadIdx.x;
  const int lane = tid & 63;
  const int wid  = tid >> 6;
  const int row  = blockIdx.x * 4 + wid;       // ((b*8+h)*256+l)
  const int b = row >> 11;
  const int h = (row >> 8) & 7;
  const int l = row & 255;
  const long qbase = ((long)(b * 256 + l) << 11) + h * 256;
  const float* kb  = (b < 16) ? kp0 : kp1;
  const long kbase = ((long)((b & 15) * 256 + l) << 11) + h * 256;

  {
    f32x4 qv = *(const f32x4*)(qp + qbase + 4 * lane);
    f32x4 kv = *(const f32x4*)(kb + kbase + 4 * lane);
    *(f32x4*)&qs[wid][4 * lane]       = qv;
    *(f32x4*)&qs[wid][256 + 4 * lane] = qv;
    *(f32x4*)&ks[wid][4 * lane]       = kv;
  }
  __syncthreads();

  float c0 = 0.f, c1 = 0.f, c2 = 0.f, c3 = 0.f;
  const int d = 4 * lane;
  const float* Q  = &qs[wid][0];
  const float* Kv = &ks[wid][0];
  #pragma unroll 4
  for (int u0 = 0; u0 < 256; u0 += 4) {
    f32x4 K4 = *(const f32x4*)(Kv + u0);
    f32x4 Qa = *(const f32x4*)(Q + u0 + d);
    f32x4 Qb = *(const f32x4*)(Q + u0 + d + 4);
    c0 += K4[0]*Qa[0] + K4[1]*Qa[1] + K4[2]*Qa[2] + K4[3]*Qa[3];
    c1 += K4[0]*Qa[1] + K4[1]*Qa[2] + K4[2]*Qa[3] + K4[3]*Qb[0];
    c2 += K4[0]*Qa[2] + K4[1]*Qa[3] + K4[2]*Qb[0] + K4[3]*Qb[1];
    c3 += K4[0]*Qa[3] + K4[1]*Qb[0] + K4[2]*Qb[1] + K4[3]*Qb[2];
  }

  const float invT = 1.0f / temp[h];
  float mx = fmaxf(fmaxf(c0, c1), fmaxf(c2, c3));
  #pragma unroll
  for (int off = 32; off >= 1; off >>= 1) mx = fmaxf(mx, __shfl_xor(mx, off, 64));
  const float e0 = __expf((c0 - mx) * invT);
  const float e1 = __expf((c1 - mx) * invT);
  const float e2 = __expf((c2 - mx) * invT);
  const float e3 = __expf((c3 - mx) * invT);
  float sm = e0 + e1 + e2 + e3;
  #pragma unroll
  for (int off = 32; off >= 1; off >>= 1) sm += __shfl_xor(sm, off, 64);
  const float rs = 1.0f / sm;
  u16x4 o;
  o[0] = f2bf(e0 * rs); o[1] = f2bf(e1 * rs); o[2] = f2bf(e2 * rs); o[3] = f2bf(e3 * rs);
  *(u16x4*)(w + (long)row * 256 + d) = o;
}

// ---------------- launcher ----------------

extern "C" void kernel_launch(void* const* d_in, const int* in_sizes, int n_in,
                              void* d_out, int out_size, void* d_ws, size_t ws_size,
                              hipStream_t stream) {
  (void)in_sizes; (void)n_in; (void)out_size; (void)ws_size;
  const float* queries = (const float*)d_in[0];
  const float* keys    = (const float*)d_in[1];
  const float* values  = (const float*)d_in[2];
  const float* Wq = (const float*)d_in[3];
  const float* bq = (const float*)d_in[4];
  const float* Wk = (const float*)d_in[5];
  const float* bk = (const float*)d_in[6];
  const float* Wv = (const float*)d_in[7];
  const float* bv = (const float*)d_in[8];
  const float* Wo = (const float*)d_in[9];
  const float* bo = (const float*)d_in[10];
  const float* temp = (const float*)d_in[11];

  // workspace (peak exactly 192 MiB) + d_out used as pack scratch:
  //  ws[0,64)   extA (packed queries/keys hi-lo) -> later wgt[0,32) + Vb[32,64)
  //             -> Wob[0,8) at the final GEMM
  //  ws[64,128) kproj fp32 -> later vT[64,96) + out2[96,128)
  //  ws[128,192) qproj fp32
  //  d_out      packed weights (extW, <=16 MiB) until the final GEMM
  char* ws = (char*)d_ws;
  auto MB = [](size_t m) { return m << 20; };
  unsigned short* extA = (unsigned short*)ws;
  unsigned short* wgt  = (unsigned short*)ws;
  unsigned short* Wob  = (unsigned short*)ws;
  unsigned short* Vb   = (unsigned short*)(ws + MB(32));
  float*          kproj= (float*)(ws + MB(64));
  unsigned short* vT   = (unsigned short*)(ws + MB(64));
  unsigned short* out2 = (unsigned short*)(ws + MB(96));
  float*          qproj= (float*)(ws + MB(128));
  unsigned short* extW = (unsigned short*)d_out;

  dim3 blk(256);
  dim3 gBig(8, 32);   // 256 blocks, 1/CU

  // ---- Q projection: triple-precision, logical K=6144 ----
  pack_hilo<<<2048, blk, 0, stream>>>(Wq, extW, 2048);
  pack_hilo<<<2048, blk, 0, stream>>>(queries, extA, 8192);
  gemm8p<3, 0><<<gBig, 512, 0, stream>>>(extA, extW, bq, qproj);
  // ---- K projection (full M=8192, contiguous kproj) ----
  pack_hilo<<<2048, blk, 0, stream>>>(Wk, extW, 2048);
  pack_hilo<<<2048, blk, 0, stream>>>(keys, extA, 8192);
  gemm8p<3, 0><<<gBig, 512, 0, stream>>>(extA, extW, bk, kproj);
  // ---- correlation + softmax -> bf16 weights ----
  corr_softmax<<<dim3(16384), blk, 0, stream>>>(qproj, kproj,
                                                kproj + (long)16 * 256 * 2048, temp, wgt);
  // ---- V projection (bf16), epilogue scatters transposed vT[b,h,i,s] ----
  pack_bf16<<<2048, blk, 0, stream>>>(values, Vb, (long)8192 * 2048 / 8);
  pack_bf16<<<2048, blk, 0, stream>>>(Wv, extW, (long)2048 * 2048 / 8);
  gemm8p<1, 1><<<gBig, 512, 0, stream>>>(Vb, extW, bv, vT);
  // ---- aggregation: out2[b*256+l][h*256+i] = sum_s wgt[bhl][s]*vT[bhi][s] ----
  fgemm<1, 2, true><<<dim3(2, 2, 256), blk, 0, stream>>>(wgt, vT, nullptr, out2,
                                                         256, 256, 2048, 256);
  // ---- O projection -> d_out (fp32) ----
  pack_bf16<<<2048, blk, 0, stream>>>(Wo, Wob, (long)2048 * 2048 / 8);
  gemm8p<1, 0><<<gBig, 512, 0, stream>>>(out2, Wob, bo, (float*)d_out);
}

// Round 5
// 775.564 us; speedup vs baseline: 1.4454x; 1.0126x over previous
//
#include <hip/hip_runtime.h>
#include <stdint.h>

typedef float  f32x4 __attribute__((ext_vector_type(4)));
typedef short  s16x8 __attribute__((ext_vector_type(8)));
typedef unsigned short u16x4 __attribute__((ext_vector_type(4)));

#define DEV __device__ __forceinline__

DEV unsigned short f2bf(float f) {
  union { float f; unsigned int u; } v; v.f = f;
  unsigned int u = v.u;
  return (unsigned short)((u + 0x7fffu + ((u >> 16) & 1u)) >> 16);
}
DEV float bf2f(unsigned short h) {
  union { unsigned int u; float f; } v; v.u = ((unsigned int)h) << 16;
  return v.f;
}

typedef const __attribute__((address_space(1))) void* as1cvp;
typedef __attribute__((address_space(3))) void* as3vp;
DEV void gload16(const void* g, void* l) {
  __builtin_amdgcn_global_load_lds((as1cvp)g, (as3vp)l, 16, 0, 0);
}

// ---------------- pack kernels (memory-bound) ----------------

// fp32 [rows][2048] -> bf16 [rows][4096] as [hi | lo]
__global__ __launch_bounds__(256) void pack_hilo(const float* __restrict__ in,
                                                 unsigned short* __restrict__ out, int rows)
{
  const long total = (long)rows * 256;
  for (long t = (long)blockIdx.x * 256 + threadIdx.x; t < total;
       t += (long)gridDim.x * 256) {
    const long r = t >> 8;
    const int  c = (int)(t & 255) * 8;
    const float* src = in + (r << 11) + c;
    f32x4 x0 = *(const f32x4*)src;
    f32x4 x1 = *(const f32x4*)(src + 4);
    s16x8 h8, l8;
    #pragma unroll
    for (int e = 0; e < 4; ++e) {
      unsigned short h0 = f2bf(x0[e]);
      unsigned short h1 = f2bf(x1[e]);
      h8[e]     = (short)h0;
      h8[e + 4] = (short)h1;
      l8[e]     = (short)f2bf(x0[e] - bf2f(h0));
      l8[e + 4] = (short)f2bf(x1[e] - bf2f(h1));
    }
    unsigned short* drow = out + (r << 12);
    *(s16x8*)(drow + c)        = h8;
    *(s16x8*)(drow + 2048 + c) = l8;
  }
}

__global__ __launch_bounds__(256) void pack_bf16(const float* __restrict__ in,
                                                 unsigned short* __restrict__ out, long total8)
{
  for (long t = (long)blockIdx.x * 256 + threadIdx.x; t < total8;
       t += (long)gridDim.x * 256) {
    const float* src = in + t * 8;
    f32x4 x0 = *(const f32x4*)src;
    f32x4 x1 = *(const f32x4*)(src + 4);
    s16x8 h8;
    #pragma unroll
    for (int e = 0; e < 4; ++e) {
      h8[e]     = (short)f2bf(x0[e]);
      h8[e + 4] = (short)f2bf(x1[e]);
    }
    *(s16x8*)(out + t * 8) = h8;
  }
}

// ---------------- 256x256 8-phase bf16 NT GEMM ----------------
// M=8192 (grid.y*256), N=2048 (grid.x*256). C[m,n] = sum_k A[m,k]*B[n,k] + bias[n].
// NSLICE 3: logical K=6144 over [hi|lo] planes (stride 4096): AhBh + AlBh + AhBl.
// OM 0: fp32 row-major (ldc 2048); OM 1: bf16 scatter vT[((b*8+h)*256+i)*256+s].
// LDS swizzle (derived for 128B rows): flip BYTE bit6 (ushort bit5, bank bit4)
// with row bit2 (ushort addr bit8). Per-phase start banks = kogrp*4 + 16*flip
// = {0,4,..,28}, 8 lanes each -> uniform 8 dwords/bank (conflict-free-equiv).
// Write side: LDS dest linear (gload_lds), source chunk-col ^= ((tid>>5)&1)<<2.
template<int NSLICE, int OM>
__global__ __launch_bounds__(512, 2)
void gemm8p(const unsigned short* __restrict__ Ap, const unsigned short* __restrict__ Bp,
            const float* __restrict__ bias, void* __restrict__ Cp)
{
  constexpr int LDA = (NSLICE == 3) ? 4096 : 2048;
  constexpr int LDB = (NSLICE == 3) ? 4096 : 2048;
  constexpr int LDC = 2048;
  constexpr int NT  = (NSLICE == 3) ? 96 : 32;   // K-tiles of 64
  constexpr int NI  = NT / 2;

  __shared__ __align__(16) unsigned short lds[65536];  // 128 KB

  const int tid  = threadIdx.x;
  const int lane = tid & 63;
  const int wid  = tid >> 6;
  const int wm   = wid >> 2;        // 0..1
  const int wn   = wid & 3;         // 0..3
  const int fr   = lane & 15;
  const int ko   = (lane >> 4) * 8;

  const int m0 = blockIdx.y * 256;
  const int n0 = blockIdx.x * 256;

  // staging: row sr = tid>>3, chunk-col (tid&7) with bank-swizzle bit2 flip
  const int sr  = tid >> 3;
  const int scc = (((tid & 7) ^ (((tid >> 5) & 1) << 2)) << 3); // src col elems

  auto sA = [&](int d, int u, int col) {
    const unsigned short* s0 = Ap + (long)(m0 + u * 64 + sr) * LDA + col + scc;
    const int lb = d * 32768 + u * 4096 + (wid << 9);
    gload16(s0, lds + lb);
    gload16(s0 + 128 * LDA, lds + lb + 8192);
  };
  auto sB = [&](int d, int h, int col) {
    const unsigned short* s0 = Bp + (long)(n0 + h * 128 + sr) * LDB + col + scc;
    const int lb = d * 32768 + 16384 + h * 8192 + (wid << 9);
    gload16(s0, lds + lb);
    gload16(s0 + 64 * LDB, lds + lb + 4096);
  };
  auto acol = [](int t) -> int {
    if (NSLICE == 3) { int sl = t >> 5, kw = (t & 31) << 6; return kw + (sl == 1 ? 2048 : 0); }
    return t << 6;
  };
  auto bcol = [](int t) -> int {
    if (NSLICE == 3) { int sl = t >> 5, kw = (t & 31) << 6; return kw + (sl == 2 ? 2048 : 0); }
    return t << 6;
  };

  f32x4 acc[8][4];
  #pragma unroll
  for (int i = 0; i < 8; ++i)
    #pragma unroll
    for (int j = 0; j < 4; ++j)
      acc[i][j] = (f32x4)(0.0f);

  s16x8 afr[2][2], bfr[4][2];

#define LOADB(d)                                                              \
  _Pragma("unroll") for (int ni = 0; ni < 4; ++ni)                            \
    _Pragma("unroll") for (int kk = 0; kk < 2; ++kk) {                        \
      const int nr = wn * 64 + ni * 16 + fr;                                  \
      int u = (d) * 32768 + 16384 + (nr >> 7) * 8192 + (nr & 127) * 64        \
              + kk * 32 + ko;                                                 \
      u ^= ((u >> 8) & 1) << 5;                                               \
      bfr[ni][kk] = *(const s16x8*)&lds[u];                                   \
    }

#define PHASE(d, q, DOB, STAGE, VM)                                           \
  {                                                                           \
    if (DOB) { LOADB(d) }                                                     \
    _Pragma("unroll") for (int ai = 0; ai < 2; ++ai)                          \
      _Pragma("unroll") for (int kk = 0; kk < 2; ++kk) {                      \
        int u = (d) * 32768 + wm * 8192 + ((2 * (q) + ai) * 16 + fr) * 64     \
                + kk * 32 + ko;                                               \
        u ^= ((u >> 8) & 1) << 5;                                             \
        afr[ai][kk] = *(const s16x8*)&lds[u];                                 \
      }                                                                       \
    STAGE;                                                                    \
    __builtin_amdgcn_s_barrier();                                             \
    asm volatile("s_waitcnt lgkmcnt(0)" ::: "memory");                        \
    __builtin_amdgcn_sched_barrier(0);                                        \
    __builtin_amdgcn_s_setprio(1);                                            \
    _Pragma("unroll") for (int ai = 0; ai < 2; ++ai)                          \
      _Pragma("unroll") for (int ni = 0; ni < 4; ++ni)                        \
        _Pragma("unroll") for (int kk = 0; kk < 2; ++kk)                      \
          acc[2 * (q) + ai][ni] = __builtin_amdgcn_mfma_f32_16x16x32_bf16(    \
              afr[ai][kk], bfr[ni][kk], acc[2 * (q) + ai][ni], 0, 0, 0);      \
    __builtin_amdgcn_s_setprio(0);                                            \
    if (VM) { asm volatile("s_waitcnt vmcnt(6)" ::: "memory"); }              \
    __builtin_amdgcn_s_barrier();                                             \
  }

  // prologue: stage tile0 fully + tile1 {B0,B1,A0}; wait; barrier
  sB(0, 0, bcol(0)); sB(0, 1, bcol(0));
  sA(0, 0, acol(0)); sA(0, 1, acol(0));
  sB(1, 0, bcol(1)); sB(1, 1, bcol(1));
  sA(1, 0, acol(1));
  asm volatile("s_waitcnt vmcnt(6)" ::: "memory");
  __builtin_amdgcn_s_barrier();

  for (int i = 0; i < NI; ++i) {
    const int t1  = 2 * i + 1;
    const int ts0 = (2 * i + 2 < NT) ? 2 * i + 2 : NT - 1;
    const int ts1 = (2 * i + 3 < NT) ? 2 * i + 3 : NT - 1;
    const int a1c = acol(t1);
    const int as0 = acol(ts0), bs0 = bcol(ts0);
    const int as1 = acol(ts1), bs1 = bcol(ts1);
    PHASE(0, 0, true,  sA(1, 1, a1c), false)
    PHASE(0, 1, false, sB(0, 0, bs0), false)
    PHASE(0, 2, false, sB(0, 1, bs0), false)
    PHASE(0, 3, false, sA(0, 0, as0), true)
    PHASE(1, 0, true,  sA(0, 1, as0), false)
    PHASE(1, 1, false, sB(1, 0, bs1), false)
    PHASE(1, 2, false, sB(1, 1, bs1), false)
    PHASE(1, 3, false, sA(1, 0, as1), true)
  }
#undef PHASE
#undef LOADB

  // epilogue: C/D frag col = lane&15 (N side), row = (lane>>4)*4 + r (M side)
  const int rg = (lane >> 4) * 4;
  #pragma unroll
  for (int ni = 0; ni < 4; ++ni) {
    const int gn = n0 + wn * 64 + ni * 16 + fr;
    const float bvl = bias[gn];
    #pragma unroll
    for (int mi = 0; mi < 8; ++mi) {
      const int gmB = m0 + wm * 128 + mi * 16 + rg;
      f32x4 v = acc[mi][ni];
      if (OM == 0) {
        float* Cf = (float*)Cp;
        #pragma unroll
        for (int r = 0; r < 4; ++r)
          Cf[(long)(gmB + r) * LDC + gn] = v[r] + bvl;
      } else { // OM == 1: vT[((b*8+h)*256 + i)*256 + s]
        const int b = gmB >> 8, s = gmB & 255, h = gn >> 8, ii = gn & 255;
        u16x4 o;
        #pragma unroll
        for (int r = 0; r < 4; ++r) o[r] = f2bf(v[r] + bvl);
        *(u16x4*)&((unsigned short*)Cp)[((long)((b * 8 + h) * 256 + ii) << 8) + s] = o;
      }
    }
  }
}

// ---------------- 128x128 NT GEMM (m97 structure) — used for aggregation ----
template<int MODE, int OM, bool BATCHED>
__global__ __launch_bounds__(256)
void fgemm(const unsigned short* __restrict__ A, const unsigned short* __restrict__ B,
           const float* __restrict__ bias, void* __restrict__ C,
           int lda, int ldb, int ldc, int KT)
{
  __shared__ __align__(16) unsigned short lA[2 * 128 * 32];
  __shared__ __align__(16) unsigned short lB[2 * 128 * 32];

  const int tid  = threadIdx.x;
  const int lane = tid & 63;
  const int wid  = tid >> 6;
  const int wr   = wid >> 1;
  const int wc   = wid & 1;

  const int z  = BATCHED ? blockIdx.z : 0;
  const int m0 = blockIdx.y * 128;
  const int n0 = blockIdx.x * 128;

  long aBase = (long)m0 * lda;
  long bBase = (long)n0 * ldb;
  if (BATCHED) {
    aBase += (long)z * 256 * lda;
    bBase += (long)z * 256 * ldb;
  }

  const int ar0 = tid >> 2, ac0 = (tid & 3) * 8;
  const int ar1 = ar0 + 64, ac1 = ac0;

  const unsigned short* pa0 = A + aBase + (long)ar0 * lda + ac0;
  const unsigned short* pa1 = A + aBase + (long)ar1 * lda + ac1;
  const unsigned short* pb0 = B + bBase + (long)ar0 * ldb + ac0;
  const unsigned short* pb1 = B + bBase + (long)ar1 * ldb + ac1;

  constexpr int SUBOFF = (MODE == 0) ? 2048 : 32;
  constexpr int KSTEP  = (MODE == 0) ? 32 : 64;

  f32x4 acc[4][4];
  #pragma unroll
  for (int i = 0; i < 4; ++i)
    #pragma unroll
    for (int j = 0; j < 4; ++j)
      acc[i][j] = (f32x4)(0.0f);

  const int fr   = lane & 15;
  const int krow = (lane >> 4) * 8;

  for (int kt = 0; kt < KT; kt += KSTEP) {
    gload16(pa0 + kt,          lA + tid * 8);
    gload16(pa1 + kt,          lA + (tid + 256) * 8);
    gload16(pa0 + kt + SUBOFF, lA + 4096 + tid * 8);
    gload16(pa1 + kt + SUBOFF, lA + 4096 + (tid + 256) * 8);
    gload16(pb0 + kt,          lB + tid * 8);
    gload16(pb1 + kt,          lB + (tid + 256) * 8);
    gload16(pb0 + kt + SUBOFF, lB + 4096 + tid * 8);
    gload16(pb1 + kt + SUBOFF, lB + 4096 + (tid + 256) * 8);
    __syncthreads();

    s16x8 a0[4], a1[4], b0[4], b1[4];
    #pragma unroll
    for (int i = 0; i < 4; ++i) {
      const int r = (wr * 64 + i * 16 + fr) * 32 + krow;
      a0[i] = *(const s16x8*)&lA[r];
      a1[i] = *(const s16x8*)&lA[4096 + r];
    }
    #pragma unroll
    for (int j = 0; j < 4; ++j) {
      const int r = (wc * 64 + j * 16 + fr) * 32 + krow;
      b0[j] = *(const s16x8*)&lB[r];
      b1[j] = *(const s16x8*)&lB[4096 + r];
    }

    #pragma unroll
    for (int i = 0; i < 4; ++i)
      #pragma unroll
      for (int j = 0; j < 4; ++j) {
        if (MODE == 0) {
          acc[i][j] = __builtin_amdgcn_mfma_f32_16x16x32_bf16(a1[i], b0[j], acc[i][j], 0, 0, 0);
          acc[i][j] = __builtin_amdgcn_mfma_f32_16x16x32_bf16(a0[i], b1[j], acc[i][j], 0, 0, 0);
          acc[i][j] = __builtin_amdgcn_mfma_f32_16x16x32_bf16(a0[i], b0[j], acc[i][j], 0, 0, 0);
        } else {
          acc[i][j] = __builtin_amdgcn_mfma_f32_16x16x32_bf16(a0[i], b0[j], acc[i][j], 0, 0, 0);
          acc[i][j] = __builtin_amdgcn_mfma_f32_16x16x32_bf16(a1[i], b1[j], acc[i][j], 0, 0, 0);
        }
      }

    __syncthreads();
  }

  const int rg = (lane >> 4) * 4;
  #pragma unroll
  for (int j = 0; j < 4; ++j) {
    const int gn = n0 + wc * 64 + j * 16 + fr;
    const float bvl = bias ? bias[gn] : 0.0f;
    #pragma unroll
    for (int i = 0; i < 4; ++i) {
      const int gmB = m0 + wr * 64 + i * 16 + rg;
      f32x4 v = acc[i][j];
      if (OM == 0) {
        float* Cf = (float*)C;
        #pragma unroll
        for (int r = 0; r < 4; ++r)
          Cf[(long)(gmB + r) * ldc + gn] = v[r] + bvl;
      } else if (OM == 2) {
        long cb = 0;
        if (BATCHED) cb = (long)(z >> 3) * 256 * ldc + (long)(z & 7) * 256;
        unsigned short* Ch = (unsigned short*)C;
        #pragma unroll
        for (int r = 0; r < 4; ++r)
          Ch[cb + (long)(gmB + r) * ldc + gn] = f2bf(v[r] + bvl);
      } else {
        const int b = gmB >> 8, s = gmB & 255, h = gn >> 8, ii = gn & 255;
        u16x4 o;
        #pragma unroll
        for (int r = 0; r < 4; ++r) o[r] = f2bf(v[r] + bvl);
        *(u16x4*)&((unsigned short*)C)[((long)((b * 8 + h) * 256 + ii) << 8) + s] = o;
      }
    }
  }
}

// ---------------- circular correlation + softmax ----------------
__global__ __launch_bounds__(256)
void corr_softmax(const float* __restrict__ qp, const float* __restrict__ kp0,
                  const float* __restrict__ kp1, const float* __restrict__ temp,
                  unsigned short* __restrict__ w)
{
  __shared__ float qs[4][520];
  __shared__ float ks[4][264];
  const int tid  = threadIdx.x;
  const int lane = tid & 63;
  const int wid  = tid >> 6;
  const int row  = blockIdx.x * 4 + wid;       // ((b*8+h)*256+l)
  const int b = row >> 11;
  const int h = (row >> 8) & 7;
  const int l = row & 255;
  const long qbase = ((long)(b * 256 + l) << 11) + h * 256;
  const float* kb  = (b < 16) ? kp0 : kp1;
  const long kbase = ((long)((b & 15) * 256 + l) << 11) + h * 256;

  {
    f32x4 qv = *(const f32x4*)(qp + qbase + 4 * lane);
    f32x4 kv = *(const f32x4*)(kb + kbase + 4 * lane);
    *(f32x4*)&qs[wid][4 * lane]       = qv;
    *(f32x4*)&qs[wid][256 + 4 * lane] = qv;
    *(f32x4*)&ks[wid][4 * lane]       = kv;
  }
  __syncthreads();

  float c0 = 0.f, c1 = 0.f, c2 = 0.f, c3 = 0.f;
  const int d = 4 * lane;
  const float* Q  = &qs[wid][0];
  const float* Kv = &ks[wid][0];
  #pragma unroll 4
  for (int u0 = 0; u0 < 256; u0 += 4) {
    f32x4 K4 = *(const f32x4*)(Kv + u0);
    f32x4 Qa = *(const f32x4*)(Q + u0 + d);
    f32x4 Qb = *(const f32x4*)(Q + u0 + d + 4);
    c0 += K4[0]*Qa[0] + K4[1]*Qa[1] + K4[2]*Qa[2] + K4[3]*Qa[3];
    c1 += K4[0]*Qa[1] + K4[1]*Qa[2] + K4[2]*Qa[3] + K4[3]*Qb[0];
    c2 += K4[0]*Qa[2] + K4[1]*Qa[3] + K4[2]*Qb[0] + K4[3]*Qb[1];
    c3 += K4[0]*Qa[3] + K4[1]*Qb[0] + K4[2]*Qb[1] + K4[3]*Qb[2];
  }

  const float invT = 1.0f / temp[h];
  float mx = fmaxf(fmaxf(c0, c1), fmaxf(c2, c3));
  #pragma unroll
  for (int off = 32; off >= 1; off >>= 1) mx = fmaxf(mx, __shfl_xor(mx, off, 64));
  const float e0 = __expf((c0 - mx) * invT);
  const float e1 = __expf((c1 - mx) * invT);
  const float e2 = __expf((c2 - mx) * invT);
  const float e3 = __expf((c3 - mx) * invT);
  float sm = e0 + e1 + e2 + e3;
  #pragma unroll
  for (int off = 32; off >= 1; off >>= 1) sm += __shfl_xor(sm, off, 64);
  const float rs = 1.0f / sm;
  u16x4 o;
  o[0] = f2bf(e0 * rs); o[1] = f2bf(e1 * rs); o[2] = f2bf(e2 * rs); o[3] = f2bf(e3 * rs);
  *(u16x4*)(w + (long)row * 256 + d) = o;
}

// ---------------- launcher ----------------

extern "C" void kernel_launch(void* const* d_in, const int* in_sizes, int n_in,
                              void* d_out, int out_size, void* d_ws, size_t ws_size,
                              hipStream_t stream) {
  (void)in_sizes; (void)n_in; (void)out_size; (void)ws_size;
  const float* queries = (const float*)d_in[0];
  const float* keys    = (const float*)d_in[1];
  const float* values  = (const float*)d_in[2];
  const float* Wq = (const float*)d_in[3];
  const float* bq = (const float*)d_in[4];
  const float* Wk = (const float*)d_in[5];
  const float* bk = (const float*)d_in[6];
  const float* Wv = (const float*)d_in[7];
  const float* bv = (const float*)d_in[8];
  const float* Wo = (const float*)d_in[9];
  const float* bo = (const float*)d_in[10];
  const float* temp = (const float*)d_in[11];

  // workspace (peak exactly 192 MiB) + d_out used as pack scratch:
  //  ws[0,64)   extA (packed queries/keys hi-lo) -> later wgt[0,32) + Vb[32,64)
  //             -> Wob[0,8) at the final GEMM
  //  ws[64,128) kproj fp32 -> later vT[64,96) + out2[96,128)
  //  ws[128,192) qproj fp32
  //  d_out      packed weights (extW, <=16 MiB) until the final GEMM
  char* ws = (char*)d_ws;
  auto MB = [](size_t m) { return m << 20; };
  unsigned short* extA = (unsigned short*)ws;
  unsigned short* wgt  = (unsigned short*)ws;
  unsigned short* Wob  = (unsigned short*)ws;
  unsigned short* Vb   = (unsigned short*)(ws + MB(32));
  float*          kproj= (float*)(ws + MB(64));
  unsigned short* vT   = (unsigned short*)(ws + MB(64));
  unsigned short* out2 = (unsigned short*)(ws + MB(96));
  float*          qproj= (float*)(ws + MB(128));
  unsigned short* extW = (unsigned short*)d_out;

  dim3 blk(256);
  dim3 gBig(8, 32);   // 256 blocks, 1/CU

  // ---- Q projection: triple-precision, logical K=6144 ----
  pack_hilo<<<2048, blk, 0, stream>>>(Wq, extW, 2048);
  pack_hilo<<<2048, blk, 0, stream>>>(queries, extA, 8192);
  gemm8p<3, 0><<<gBig, 512, 0, stream>>>(extA, extW, bq, qproj);
  // ---- K projection (full M=8192, contiguous kproj) ----
  pack_hilo<<<2048, blk, 0, stream>>>(Wk, extW, 2048);
  pack_hilo<<<2048, blk, 0, stream>>>(keys, extA, 8192);
  gemm8p<3, 0><<<gBig, 512, 0, stream>>>(extA, extW, bk, kproj);
  // ---- correlation + softmax -> bf16 weights ----
  corr_softmax<<<dim3(16384), blk, 0, stream>>>(qproj, kproj,
                                                kproj + (long)16 * 256 * 2048, temp, wgt);
  // ---- V projection (bf16), epilogue scatters transposed vT[b,h,i,s] ----
  pack_bf16<<<2048, blk, 0, stream>>>(values, Vb, (long)8192 * 2048 / 8);
  pack_bf16<<<2048, blk, 0, stream>>>(Wv, extW, (long)2048 * 2048 / 8);
  gemm8p<1, 1><<<gBig, 512, 0, stream>>>(Vb, extW, bv, vT);
  // ---- aggregation: out2[b*256+l][h*256+i] = sum_s wgt[bhl][s]*vT[bhi][s] ----
  fgemm<1, 2, true><<<dim3(2, 2, 256), blk, 0, stream>>>(wgt, vT, nullptr, out2,
                                                         256, 256, 2048, 256);
  // ---- O projection -> d_out (fp32) ----
  pack_bf16<<<2048, blk, 0, stream>>>(Wo, Wob, (long)2048 * 2048 / 8);
  gemm8p<1, 0><<<gBig, 512, 0, stream>>>(out2, Wob, bo, (float*)d_out);
}

// Round 6
// 743.317 us; speedup vs baseline: 1.5081x; 1.0434x over previous
//
#include <hip/hip_runtime.h>
#include <stdint.h>

typedef float  f32x4 __attribute__((ext_vector_type(4)));
typedef short  s16x8 __attribute__((ext_vector_type(8)));
typedef unsigned short u16x4 __attribute__((ext_vector_type(4)));

#define DEV __device__ __forceinline__

DEV unsigned short f2bf(float f) {
  union { float f; unsigned int u; } v; v.f = f;
  unsigned int u = v.u;
  return (unsigned short)((u + 0x7fffu + ((u >> 16) & 1u)) >> 16);
}
DEV float bf2f(unsigned short h) {
  union { unsigned int u; float f; } v; v.u = ((unsigned int)h) << 16;
  return v.f;
}

typedef const __attribute__((address_space(1))) void* as1cvp;
typedef __attribute__((address_space(3))) void* as3vp;
DEV void gload16(const void* g, void* l) {
  __builtin_amdgcn_global_load_lds((as1cvp)g, (as3vp)l, 16, 0, 0);
}

// ---------------- pack kernels (memory-bound) ----------------

// fp32 [rows][2048] -> bf16 [rows][4096] as [hi | lo]
__global__ __launch_bounds__(256) void pack_hilo(const float* __restrict__ in,
                                                 unsigned short* __restrict__ out, int rows)
{
  const long total = (long)rows * 256;
  for (long t = (long)blockIdx.x * 256 + threadIdx.x; t < total;
       t += (long)gridDim.x * 256) {
    const long r = t >> 8;
    const int  c = (int)(t & 255) * 8;
    const float* src = in + (r << 11) + c;
    f32x4 x0 = *(const f32x4*)src;
    f32x4 x1 = *(const f32x4*)(src + 4);
    s16x8 h8, l8;
    #pragma unroll
    for (int e = 0; e < 4; ++e) {
      unsigned short h0 = f2bf(x0[e]);
      unsigned short h1 = f2bf(x1[e]);
      h8[e]     = (short)h0;
      h8[e + 4] = (short)h1;
      l8[e]     = (short)f2bf(x0[e] - bf2f(h0));
      l8[e + 4] = (short)f2bf(x1[e] - bf2f(h1));
    }
    unsigned short* drow = out + (r << 12);
    *(s16x8*)(drow + c)        = h8;
    *(s16x8*)(drow + 2048 + c) = l8;
  }
}

__global__ __launch_bounds__(256) void pack_bf16(const float* __restrict__ in,
                                                 unsigned short* __restrict__ out, long total8)
{
  for (long t = (long)blockIdx.x * 256 + threadIdx.x; t < total8;
       t += (long)gridDim.x * 256) {
    const float* src = in + t * 8;
    f32x4 x0 = *(const f32x4*)src;
    f32x4 x1 = *(const f32x4*)(src + 4);
    s16x8 h8;
    #pragma unroll
    for (int e = 0; e < 4; ++e) {
      h8[e]     = (short)f2bf(x0[e]);
      h8[e + 4] = (short)f2bf(x1[e]);
    }
    *(s16x8*)(out + t * 8) = h8;
  }
}

// ---------------- 256x256 8-phase bf16 NT GEMM ----------------
// Grid (32, 8): bx -> M-block via XCD remap (xcd = bid%8 = bx&7 owns M-panels
// (bx&7)*4..+3 -> per-XCD A-panel locality), by -> N-block.
// C[m,n] = sum_k A[m,k]*B[n,k] + bias[n].
// NSLICE 3: logical K tiles t: product p = t%3 in order {AhBh, AhBl, AlBh},
//   window kw = (t/3)*64 -> hi-plane re-stages are 1-2 tiles apart (L2-hot).
// OM 0: fp32 row-major (ldc 2048); OM 1: bf16 scatter vT[((b*8+h)*256+i)*256+s].
// LDS swizzle: read u ^= ((u>>8)&1)<<5 (bank-bit4 by row-bit2); write side via
// source chunk-col ^ ((tid>>5)&1)<<2 (same involution, LDS dest linear).
template<int NSLICE, int OM>
__global__ __launch_bounds__(512, 2)
void gemm8p(const unsigned short* __restrict__ Ap, const unsigned short* __restrict__ Bp,
            const float* __restrict__ bias, void* __restrict__ Cp)
{
  constexpr int LDA = (NSLICE == 3) ? 4096 : 2048;
  constexpr int LDB = (NSLICE == 3) ? 4096 : 2048;
  constexpr int LDC = 2048;
  constexpr int NT  = (NSLICE == 3) ? 96 : 32;   // K-tiles of 64
  constexpr int NI  = NT / 2;

  __shared__ __align__(16) unsigned short lds[65536];  // 128 KB

  const int tid  = threadIdx.x;
  const int lane = tid & 63;
  const int wid  = tid >> 6;
  const int wm   = wid >> 2;        // 0..1
  const int wn   = wid & 3;         // 0..3
  const int fr   = lane & 15;
  const int ko   = (lane >> 4) * 8;

  const int bx = blockIdx.x;                       // 0..31
  const int m0 = (((bx & 7) << 2) + (bx >> 3)) * 256;
  const int n0 = blockIdx.y * 256;

  // staging: row sr = tid>>3, chunk-col (tid&7) with bank-swizzle bit2 flip
  const int sr  = tid >> 3;
  const int scc = (((tid & 7) ^ (((tid >> 5) & 1) << 2)) << 3); // src col elems

  auto sA = [&](int d, int u, int col) {
    const unsigned short* s0 = Ap + (long)(m0 + u * 64 + sr) * LDA + col + scc;
    const int lb = d * 32768 + u * 4096 + (wid << 9);
    gload16(s0, lds + lb);
    gload16(s0 + 128 * LDA, lds + lb + 8192);
  };
  auto sB = [&](int d, int h, int col) {
    const unsigned short* s0 = Bp + (long)(n0 + h * 128 + sr) * LDB + col + scc;
    const int lb = d * 32768 + 16384 + h * 8192 + (wid << 9);
    gload16(s0, lds + lb);
    gload16(s0 + 64 * LDB, lds + lb + 4096);
  };
  // product order per window: p0 = AhBh, p1 = AhBl, p2 = AlBh
  auto acol = [](int t) -> int {
    if (NSLICE == 3) { int p = t % 3, kw = (t / 3) << 6; return kw + (p == 2 ? 2048 : 0); }
    return t << 6;
  };
  auto bcol = [](int t) -> int {
    if (NSLICE == 3) { int p = t % 3, kw = (t / 3) << 6; return kw + (p == 1 ? 2048 : 0); }
    return t << 6;
  };

  f32x4 acc[8][4];
  #pragma unroll
  for (int i = 0; i < 8; ++i)
    #pragma unroll
    for (int j = 0; j < 4; ++j)
      acc[i][j] = (f32x4)(0.0f);

  s16x8 afr[2][2], bfr[4][2];

#define LOADB(d)                                                              \
  _Pragma("unroll") for (int ni = 0; ni < 4; ++ni)                            \
    _Pragma("unroll") for (int kk = 0; kk < 2; ++kk) {                        \
      const int nr = wn * 64 + ni * 16 + fr;                                  \
      int u = (d) * 32768 + 16384 + (nr >> 7) * 8192 + (nr & 127) * 64        \
              + kk * 32 + ko;                                                 \
      u ^= ((u >> 8) & 1) << 5;                                               \
      bfr[ni][kk] = *(const s16x8*)&lds[u];                                   \
    }

#define PHASE(d, q, DOB, STAGE, VM)                                           \
  {                                                                           \
    if (DOB) { LOADB(d) }                                                     \
    _Pragma("unroll") for (int ai = 0; ai < 2; ++ai)                          \
      _Pragma("unroll") for (int kk = 0; kk < 2; ++kk) {                      \
        int u = (d) * 32768 + wm * 8192 + ((2 * (q) + ai) * 16 + fr) * 64     \
                + kk * 32 + ko;                                               \
        u ^= ((u >> 8) & 1) << 5;                                             \
        afr[ai][kk] = *(const s16x8*)&lds[u];                                 \
      }                                                                       \
    STAGE;                                                                    \
    __builtin_amdgcn_s_barrier();                                             \
    asm volatile("s_waitcnt lgkmcnt(0)" ::: "memory");                        \
    __builtin_amdgcn_sched_barrier(0);                                        \
    __builtin_amdgcn_s_setprio(1);                                            \
    _Pragma("unroll") for (int ai = 0; ai < 2; ++ai)                          \
      _Pragma("unroll") for (int ni = 0; ni < 4; ++ni)                        \
        _Pragma("unroll") for (int kk = 0; kk < 2; ++kk)                      \
          acc[2 * (q) + ai][ni] = __builtin_amdgcn_mfma_f32_16x16x32_bf16(    \
              afr[ai][kk], bfr[ni][kk], acc[2 * (q) + ai][ni], 0, 0, 0);      \
    __builtin_amdgcn_s_setprio(0);                                            \
    if (VM) { asm volatile("s_waitcnt vmcnt(6)" ::: "memory"); }              \
    __builtin_amdgcn_s_barrier();                                             \
  }

  // prologue: stage tile0 fully + tile1 {B0,B1,A0}; wait; barrier
  sB(0, 0, bcol(0)); sB(0, 1, bcol(0));
  sA(0, 0, acol(0)); sA(0, 1, acol(0));
  sB(1, 0, bcol(1)); sB(1, 1, bcol(1));
  sA(1, 0, acol(1));
  asm volatile("s_waitcnt vmcnt(6)" ::: "memory");
  __builtin_amdgcn_s_barrier();

  for (int i = 0; i < NI; ++i) {
    const int t1  = 2 * i + 1;
    const int ts0 = (2 * i + 2 < NT) ? 2 * i + 2 : NT - 1;
    const int ts1 = (2 * i + 3 < NT) ? 2 * i + 3 : NT - 1;
    const int a1c = acol(t1);
    const int as0 = acol(ts0), bs0 = bcol(ts0);
    const int as1 = acol(ts1), bs1 = bcol(ts1);
    PHASE(0, 0, true,  sA(1, 1, a1c), false)
    PHASE(0, 1, false, sB(0, 0, bs0), false)
    PHASE(0, 2, false, sB(0, 1, bs0), false)
    PHASE(0, 3, false, sA(0, 0, as0), true)
    PHASE(1, 0, true,  sA(0, 1, as0), false)
    PHASE(1, 1, false, sB(1, 0, bs1), false)
    PHASE(1, 2, false, sB(1, 1, bs1), false)
    PHASE(1, 3, false, sA(1, 0, as1), true)
  }
#undef PHASE
#undef LOADB

  // epilogue: C/D frag col = lane&15 (N side), row = (lane>>4)*4 + r (M side)
  const int rg = (lane >> 4) * 4;
  #pragma unroll
  for (int ni = 0; ni < 4; ++ni) {
    const int gn = n0 + wn * 64 + ni * 16 + fr;
    const float bvl = bias[gn];
    #pragma unroll
    for (int mi = 0; mi < 8; ++mi) {
      const int gmB = m0 + wm * 128 + mi * 16 + rg;
      f32x4 v = acc[mi][ni];
      if (OM == 0) {
        float* Cf = (float*)Cp;
        #pragma unroll
        for (int r = 0; r < 4; ++r)
          Cf[(long)(gmB + r) * LDC + gn] = v[r] + bvl;
      } else { // OM == 1: vT[((b*8+h)*256 + i)*256 + s]
        const int b = gmB >> 8, s = gmB & 255, h = gn >> 8, ii = gn & 255;
        u16x4 o;
        #pragma unroll
        for (int r = 0; r < 4; ++r) o[r] = f2bf(v[r] + bvl);
        *(u16x4*)&((unsigned short*)Cp)[((long)((b * 8 + h) * 256 + ii) << 8) + s] = o;
      }
    }
  }
}

// ---------------- 128x128 NT GEMM (m97 structure) — used for aggregation ----
template<int MODE, int OM, bool BATCHED>
__global__ __launch_bounds__(256)
void fgemm(const unsigned short* __restrict__ A, const unsigned short* __restrict__ B,
           const float* __restrict__ bias, void* __restrict__ C,
           int lda, int ldb, int ldc, int KT)
{
  __shared__ __align__(16) unsigned short lA[2 * 128 * 32];
  __shared__ __align__(16) unsigned short lB[2 * 128 * 32];

  const int tid  = threadIdx.x;
  const int lane = tid & 63;
  const int wid  = tid >> 6;
  const int wr   = wid >> 1;
  const int wc   = wid & 1;

  const int z  = BATCHED ? blockIdx.z : 0;
  const int m0 = blockIdx.y * 128;
  const int n0 = blockIdx.x * 128;

  long aBase = (long)m0 * lda;
  long bBase = (long)n0 * ldb;
  if (BATCHED) {
    aBase += (long)z * 256 * lda;
    bBase += (long)z * 256 * ldb;
  }

  const int ar0 = tid >> 2, ac0 = (tid & 3) * 8;
  const int ar1 = ar0 + 64, ac1 = ac0;

  const unsigned short* pa0 = A + aBase + (long)ar0 * lda + ac0;
  const unsigned short* pa1 = A + aBase + (long)ar1 * lda + ac1;
  const unsigned short* pb0 = B + bBase + (long)ar0 * ldb + ac0;
  const unsigned short* pb1 = B + bBase + (long)ar1 * ldb + ac1;

  constexpr int SUBOFF = (MODE == 0) ? 2048 : 32;
  constexpr int KSTEP  = (MODE == 0) ? 32 : 64;

  f32x4 acc[4][4];
  #pragma unroll
  for (int i = 0; i < 4; ++i)
    #pragma unroll
    for (int j = 0; j < 4; ++j)
      acc[i][j] = (f32x4)(0.0f);

  const int fr   = lane & 15;
  const int krow = (lane >> 4) * 8;

  for (int kt = 0; kt < KT; kt += KSTEP) {
    gload16(pa0 + kt,          lA + tid * 8);
    gload16(pa1 + kt,          lA + (tid + 256) * 8);
    gload16(pa0 + kt + SUBOFF, lA + 4096 + tid * 8);
    gload16(pa1 + kt + SUBOFF, lA + 4096 + (tid + 256) * 8);
    gload16(pb0 + kt,          lB + tid * 8);
    gload16(pb1 + kt,          lB + (tid + 256) * 8);
    gload16(pb0 + kt + SUBOFF, lB + 4096 + tid * 8);
    gload16(pb1 + kt + SUBOFF, lB + 4096 + (tid + 256) * 8);
    __syncthreads();

    s16x8 a0[4], a1[4], b0[4], b1[4];
    #pragma unroll
    for (int i = 0; i < 4; ++i) {
      const int r = (wr * 64 + i * 16 + fr) * 32 + krow;
      a0[i] = *(const s16x8*)&lA[r];
      a1[i] = *(const s16x8*)&lA[4096 + r];
    }
    #pragma unroll
    for (int j = 0; j < 4; ++j) {
      const int r = (wc * 64 + j * 16 + fr) * 32 + krow;
      b0[j] = *(const s16x8*)&lB[r];
      b1[j] = *(const s16x8*)&lB[4096 + r];
    }

    #pragma unroll
    for (int i = 0; i < 4; ++i)
      #pragma unroll
      for (int j = 0; j < 4; ++j) {
        if (MODE == 0) {
          acc[i][j] = __builtin_amdgcn_mfma_f32_16x16x32_bf16(a1[i], b0[j], acc[i][j], 0, 0, 0);
          acc[i][j] = __builtin_amdgcn_mfma_f32_16x16x32_bf16(a0[i], b1[j], acc[i][j], 0, 0, 0);
          acc[i][j] = __builtin_amdgcn_mfma_f32_16x16x32_bf16(a0[i], b0[j], acc[i][j], 0, 0, 0);
        } else {
          acc[i][j] = __builtin_amdgcn_mfma_f32_16x16x32_bf16(a0[i], b0[j], acc[i][j], 0, 0, 0);
          acc[i][j] = __builtin_amdgcn_mfma_f32_16x16x32_bf16(a1[i], b1[j], acc[i][j], 0, 0, 0);
        }
      }

    __syncthreads();
  }

  const int rg = (lane >> 4) * 4;
  #pragma unroll
  for (int j = 0; j < 4; ++j) {
    const int gn = n0 + wc * 64 + j * 16 + fr;
    const float bvl = bias ? bias[gn] : 0.0f;
    #pragma unroll
    for (int i = 0; i < 4; ++i) {
      const int gmB = m0 + wr * 64 + i * 16 + rg;
      f32x4 v = acc[i][j];
      if (OM == 0) {
        float* Cf = (float*)C;
        #pragma unroll
        for (int r = 0; r < 4; ++r)
          Cf[(long)(gmB + r) * ldc + gn] = v[r] + bvl;
      } else if (OM == 2) {
        long cb = 0;
        if (BATCHED) cb = (long)(z >> 3) * 256 * ldc + (long)(z & 7) * 256;
        unsigned short* Ch = (unsigned short*)C;
        #pragma unroll
        for (int r = 0; r < 4; ++r)
          Ch[cb + (long)(gmB + r) * ldc + gn] = f2bf(v[r] + bvl);
      } else {
        const int b = gmB >> 8, s = gmB & 255, h = gn >> 8, ii = gn & 255;
        u16x4 o;
        #pragma unroll
        for (int r = 0; r < 4; ++r) o[r] = f2bf(v[r] + bvl);
        *(u16x4*)&((unsigned short*)C)[((long)((b * 8 + h) * 256 + ii) << 8) + s] = o;
      }
    }
  }
}

// ---------------- circular correlation + softmax ----------------
__global__ __launch_bounds__(256)
void corr_softmax(const float* __restrict__ qp, const float* __restrict__ kp0,
                  const float* __restrict__ kp1, const float* __restrict__ temp,
                  unsigned short* __restrict__ w)
{
  __shared__ float qs[4][520];
  __shared__ float ks[4][264];
  const int tid  = threadIdx.x;
  const int lane = tid & 63;
  const int wid  = tid >> 6;
  const int row  = blockIdx.x * 4 + wid;       // ((b*8+h)*256+l)
  const int b = row >> 11;
  const int h = (row >> 8) & 7;
  const int l = row & 255;
  const long qbase = ((long)(b * 256 + l) << 11) + h * 256;
  const float* kb  = (b < 16) ? kp0 : kp1;
  const long kbase = ((long)((b & 15) * 256 + l) << 11) + h * 256;

  {
    f32x4 qv = *(const f32x4*)(qp + qbase + 4 * lane);
    f32x4 kv = *(const f32x4*)(kb + kbase + 4 * lane);
    *(f32x4*)&qs[wid][4 * lane]       = qv;
    *(f32x4*)&qs[wid][256 + 4 * lane] = qv;
    *(f32x4*)&ks[wid][4 * lane]       = kv;
  }
  __syncthreads();

  float c0 = 0.f, c1 = 0.f, c2 = 0.f, c3 = 0.f;
  const int d = 4 * lane;
  const float* Q  = &qs[wid][0];
  const float* Kv = &ks[wid][0];
  #pragma unroll 4
  for (int u0 = 0; u0 < 256; u0 += 4) {
    f32x4 K4 = *(const f32x4*)(Kv + u0);
    f32x4 Qa = *(const f32x4*)(Q + u0 + d);
    f32x4 Qb = *(const f32x4*)(Q + u0 + d + 4);
    c0 += K4[0]*Qa[0] + K4[1]*Qa[1] + K4[2]*Qa[2] + K4[3]*Qa[3];
    c1 += K4[0]*Qa[1] + K4[1]*Qa[2] + K4[2]*Qa[3] + K4[3]*Qb[0];
    c2 += K4[0]*Qa[2] + K4[1]*Qa[3] + K4[2]*Qb[0] + K4[3]*Qb[1];
    c3 += K4[0]*Qa[3] + K4[1]*Qb[0] + K4[2]*Qb[1] + K4[3]*Qb[2];
  }

  const float invT = 1.0f / temp[h];
  float mx = fmaxf(fmaxf(c0, c1), fmaxf(c2, c3));
  #pragma unroll
  for (int off = 32; off >= 1; off >>= 1) mx = fmaxf(mx, __shfl_xor(mx, off, 64));
  const float e0 = __expf((c0 - mx) * invT);
  const float e1 = __expf((c1 - mx) * invT);
  const float e2 = __expf((c2 - mx) * invT);
  const float e3 = __expf((c3 - mx) * invT);
  float sm = e0 + e1 + e2 + e3;
  #pragma unroll
  for (int off = 32; off >= 1; off >>= 1) sm += __shfl_xor(sm, off, 64);
  const float rs = 1.0f / sm;
  u16x4 o;
  o[0] = f2bf(e0 * rs); o[1] = f2bf(e1 * rs); o[2] = f2bf(e2 * rs); o[3] = f2bf(e3 * rs);
  *(u16x4*)(w + (long)row * 256 + d) = o;
}

// ---------------- launcher ----------------

extern "C" void kernel_launch(void* const* d_in, const int* in_sizes, int n_in,
                              void* d_out, int out_size, void* d_ws, size_t ws_size,
                              hipStream_t stream) {
  (void)in_sizes; (void)n_in; (void)out_size; (void)ws_size;
  const float* queries = (const float*)d_in[0];
  const float* keys    = (const float*)d_in[1];
  const float* values  = (const float*)d_in[2];
  const float* Wq = (const float*)d_in[3];
  const float* bq = (const float*)d_in[4];
  const float* Wk = (const float*)d_in[5];
  const float* bk = (const float*)d_in[6];
  const float* Wv = (const float*)d_in[7];
  const float* bv = (const float*)d_in[8];
  const float* Wo = (const float*)d_in[9];
  const float* bo = (const float*)d_in[10];
  const float* temp = (const float*)d_in[11];

  // workspace (peak exactly 192 MiB) + d_out used as pack scratch:
  //  ws[0,64)   extA (packed queries/keys hi-lo) -> later wgt[0,32) + Vb[32,64)
  //             -> Wob[0,8) at the final GEMM
  //  ws[64,128) kproj fp32 -> later vT[64,96) + out2[96,128)
  //  ws[128,192) qproj fp32
  //  d_out      packed weights (extW, <=16 MiB) until the final GEMM
  char* ws = (char*)d_ws;
  auto MB = [](size_t m) { return m << 20; };
  unsigned short* extA = (unsigned short*)ws;
  unsigned short* wgt  = (unsigned short*)ws;
  unsigned short* Wob  = (unsigned short*)ws;
  unsigned short* Vb   = (unsigned short*)(ws + MB(32));
  float*          kproj= (float*)(ws + MB(64));
  unsigned short* vT   = (unsigned short*)(ws + MB(64));
  unsigned short* out2 = (unsigned short*)(ws + MB(96));
  float*          qproj= (float*)(ws + MB(128));
  unsigned short* extW = (unsigned short*)d_out;

  dim3 blk(256);
  dim3 gBig(32, 8);   // 256 blocks; bx -> M (XCD-remapped in-kernel), by -> N

  // ---- Q projection: triple-precision, logical K=6144 ----
  pack_hilo<<<2048, blk, 0, stream>>>(Wq, extW, 2048);
  pack_hilo<<<2048, blk, 0, stream>>>(queries, extA, 8192);
  gemm8p<3, 0><<<gBig, 512, 0, stream>>>(extA, extW, bq, qproj);
  // ---- K projection (full M=8192, contiguous kproj) ----
  pack_hilo<<<2048, blk, 0, stream>>>(Wk, extW, 2048);
  pack_hilo<<<2048, blk, 0, stream>>>(keys, extA, 8192);
  gemm8p<3, 0><<<gBig, 512, 0, stream>>>(extA, extW, bk, kproj);
  // ---- correlation + softmax -> bf16 weights ----
  corr_softmax<<<dim3(16384), blk, 0, stream>>>(qproj, kproj,
                                                kproj + (long)16 * 256 * 2048, temp, wgt);
  // ---- V projection (bf16), epilogue scatters transposed vT[b,h,i,s] ----
  pack_bf16<<<2048, blk, 0, stream>>>(values, Vb, (long)8192 * 2048 / 8);
  pack_bf16<<<2048, blk, 0, stream>>>(Wv, extW, (long)2048 * 2048 / 8);
  gemm8p<1, 1><<<gBig, 512, 0, stream>>>(Vb, extW, bv, vT);
  // ---- aggregation: out2[b*256+l][h*256+i] = sum_s wgt[bhl][s]*vT[bhi][s] ----
  fgemm<1, 2, true><<<dim3(2, 2, 256), blk, 0, stream>>>(wgt, vT, nullptr, out2,
                                                         256, 256, 2048, 256);
  // ---- O projection -> d_out (fp32) ----
  pack_bf16<<<2048, blk, 0, stream>>>(Wo, Wob, (long)2048 * 2048 / 8);
  gemm8p<1, 0><<<gBig, 512, 0, stream>>>(out2, Wob, bo, (float*)d_out);
}

// Round 7
// 510.943 us; speedup vs baseline: 2.1940x; 1.4548x over previous
//
#include <hip/hip_runtime.h>
#include <stdint.h>

typedef float  f32x4 __attribute__((ext_vector_type(4)));
typedef float  f32x2 __attribute__((ext_vector_type(2)));
typedef short  s16x8 __attribute__((ext_vector_type(8)));
typedef _Float16 h16x8 __attribute__((ext_vector_type(8)));
typedef unsigned short u16x4 __attribute__((ext_vector_type(4)));

#define DEV __device__ __forceinline__

DEV unsigned short f2bf(float f) {
  union { float f; unsigned int u; } v; v.f = f;
  unsigned int u = v.u;
  return (unsigned short)((u + 0x7fffu + ((u >> 16) & 1u)) >> 16);
}

typedef const __attribute__((address_space(1))) void* as1cvp;
typedef __attribute__((address_space(3))) void* as3vp;
DEV void gload16(const void* g, void* l) {
  __builtin_amdgcn_global_load_lds((as1cvp)g, (as3vp)l, 16, 0, 0);
}

// ---------------- pack kernels (memory-bound) ----------------

// fp32 -> fp16 flat (total8 = count/8)
__global__ __launch_bounds__(256) void pack_f16(const float* __restrict__ in,
                                                unsigned short* __restrict__ out, long total8)
{
  for (long t = (long)blockIdx.x * 256 + threadIdx.x; t < total8;
       t += (long)gridDim.x * 256) {
    const float* src = in + t * 8;
    f32x4 x0 = *(const f32x4*)src;
    f32x4 x1 = *(const f32x4*)(src + 4);
    s16x8 h8;
    #pragma unroll
    for (int e = 0; e < 4; ++e) {
      h8[e]     = (short)__builtin_bit_cast(unsigned short, (_Float16)x0[e]);
      h8[e + 4] = (short)__builtin_bit_cast(unsigned short, (_Float16)x1[e]);
    }
    *(s16x8*)(out + t * 8) = h8;
  }
}

// fp32 -> bf16 flat
__global__ __launch_bounds__(256) void pack_bf16(const float* __restrict__ in,
                                                 unsigned short* __restrict__ out, long total8)
{
  for (long t = (long)blockIdx.x * 256 + threadIdx.x; t < total8;
       t += (long)gridDim.x * 256) {
    const float* src = in + t * 8;
    f32x4 x0 = *(const f32x4*)src;
    f32x4 x1 = *(const f32x4*)(src + 4);
    s16x8 h8;
    #pragma unroll
    for (int e = 0; e < 4; ++e) {
      h8[e]     = (short)f2bf(x0[e]);
      h8[e + 4] = (short)f2bf(x1[e]);
    }
    *(s16x8*)(out + t * 8) = h8;
  }
}

// ---------------- 256x256 8-phase NT GEMM (bf16 or fp16) ----------------
// Grid (32, 8): bx -> M-block via XCD remap (xcd = bx&7 owns M-panels
// (bx&7)*4..+3), by -> N-block. C[m,n] = sum_k A[m,k]*B[n,k] + bias[n].
// DT 0: bf16 MFMA; DT 1: fp16 MFMA (same fragment geometry). K = 2048.
// OM 0: fp32 row-major (ldc 2048); OM 1: bf16 scatter vT[((b*8+h)*256+i)*256+s].
// LDS swizzle: read u ^= ((u>>8)&1)<<5 (bank-bit4 by row-bit2); write side via
// source chunk-col ^ ((tid>>5)&1)<<2 (same involution, LDS dest linear).
template<int DT>
DEV f32x4 mfma16(s16x8 a, s16x8 b, f32x4 c) {
  if constexpr (DT == 0)
    return __builtin_amdgcn_mfma_f32_16x16x32_bf16(a, b, c, 0, 0, 0);
  else
    return __builtin_amdgcn_mfma_f32_16x16x32_f16(
        __builtin_bit_cast(h16x8, a), __builtin_bit_cast(h16x8, b), c, 0, 0, 0);
}

template<int DT, int OM>
__global__ __launch_bounds__(512, 2)
void gemm8p(const unsigned short* __restrict__ Ap, const unsigned short* __restrict__ Bp,
            const float* __restrict__ bias, void* __restrict__ Cp)
{
  constexpr int LD  = 2048;
  constexpr int LDC = 2048;
  constexpr int NT  = 32;    // K-tiles of 64
  constexpr int NI  = NT / 2;

  __shared__ __align__(16) unsigned short lds[65536];  // 128 KB

  const int tid  = threadIdx.x;
  const int lane = tid & 63;
  const int wid  = tid >> 6;
  const int wm   = wid >> 2;        // 0..1
  const int wn   = wid & 3;         // 0..3
  const int fr   = lane & 15;
  const int ko   = (lane >> 4) * 8;

  const int bx = blockIdx.x;                       // 0..31
  const int m0 = (((bx & 7) << 2) + (bx >> 3)) * 256;
  const int n0 = blockIdx.y * 256;

  // staging: row sr = tid>>3, chunk-col (tid&7) with bank-swizzle bit2 flip
  const int sr  = tid >> 3;
  const int scc = (((tid & 7) ^ (((tid >> 5) & 1) << 2)) << 3); // src col elems

  auto sA = [&](int d, int u, int col) {
    const unsigned short* s0 = Ap + (long)(m0 + u * 64 + sr) * LD + col + scc;
    const int lb = d * 32768 + u * 4096 + (wid << 9);
    gload16(s0, lds + lb);
    gload16(s0 + 128 * LD, lds + lb + 8192);
  };
  auto sB = [&](int d, int h, int col) {
    const unsigned short* s0 = Bp + (long)(n0 + h * 128 + sr) * LD + col + scc;
    const int lb = d * 32768 + 16384 + h * 8192 + (wid << 9);
    gload16(s0, lds + lb);
    gload16(s0 + 64 * LD, lds + lb + 4096);
  };

  f32x4 acc[8][4];
  #pragma unroll
  for (int i = 0; i < 8; ++i)
    #pragma unroll
    for (int j = 0; j < 4; ++j)
      acc[i][j] = (f32x4)(0.0f);

  s16x8 afr[2][2], bfr[4][2];

#define LOADB(d)                                                              \
  _Pragma("unroll") for (int ni = 0; ni < 4; ++ni)                            \
    _Pragma("unroll") for (int kk = 0; kk < 2; ++kk) {                        \
      const int nr = wn * 64 + ni * 16 + fr;                                  \
      int u = (d) * 32768 + 16384 + (nr >> 7) * 8192 + (nr & 127) * 64        \
              + kk * 32 + ko;                                                 \
      u ^= ((u >> 8) & 1) << 5;                                               \
      bfr[ni][kk] = *(const s16x8*)&lds[u];                                   \
    }

#define PHASE(d, q, DOB, STAGE, VM)                                           \
  {                                                                           \
    if (DOB) { LOADB(d) }                                                     \
    _Pragma("unroll") for (int ai = 0; ai < 2; ++ai)                          \
      _Pragma("unroll") for (int kk = 0; kk < 2; ++kk) {                      \
        int u = (d) * 32768 + wm * 8192 + ((2 * (q) + ai) * 16 + fr) * 64     \
                + kk * 32 + ko;                                               \
        u ^= ((u >> 8) & 1) << 5;                                             \
        afr[ai][kk] = *(const s16x8*)&lds[u];                                 \
      }                                                                       \
    STAGE;                                                                    \
    __builtin_amdgcn_s_barrier();                                             \
    asm volatile("s_waitcnt lgkmcnt(0)" ::: "memory");                        \
    __builtin_amdgcn_sched_barrier(0);                                        \
    __builtin_amdgcn_s_setprio(1);                                            \
    _Pragma("unroll") for (int ai = 0; ai < 2; ++ai)                          \
      _Pragma("unroll") for (int ni = 0; ni < 4; ++ni)                        \
        _Pragma("unroll") for (int kk = 0; kk < 2; ++kk)                      \
          acc[2 * (q) + ai][ni] =                                             \
              mfma16<DT>(afr[ai][kk], bfr[ni][kk], acc[2 * (q) + ai][ni]);    \
    __builtin_amdgcn_s_setprio(0);                                            \
    if (VM) { asm volatile("s_waitcnt vmcnt(6)" ::: "memory"); }              \
    __builtin_amdgcn_s_barrier();                                             \
  }

  // prologue: stage tile0 fully + tile1 {B0,B1,A0}; wait; barrier
  sB(0, 0, 0); sB(0, 1, 0);
  sA(0, 0, 0); sA(0, 1, 0);
  sB(1, 0, 64); sB(1, 1, 64);
  sA(1, 0, 64);
  asm volatile("s_waitcnt vmcnt(6)" ::: "memory");
  __builtin_amdgcn_s_barrier();

  for (int i = 0; i < NI; ++i) {
    const int a1c = (2 * i + 1) << 6;
    const int c0  = ((2 * i + 2 < NT) ? 2 * i + 2 : NT - 1) << 6;
    const int c1  = ((2 * i + 3 < NT) ? 2 * i + 3 : NT - 1) << 6;
    PHASE(0, 0, true,  sA(1, 1, a1c), false)
    PHASE(0, 1, false, sB(0, 0, c0), false)
    PHASE(0, 2, false, sB(0, 1, c0), false)
    PHASE(0, 3, false, sA(0, 0, c0), true)
    PHASE(1, 0, true,  sA(0, 1, c0), false)
    PHASE(1, 1, false, sB(1, 0, c1), false)
    PHASE(1, 2, false, sB(1, 1, c1), false)
    PHASE(1, 3, false, sA(1, 0, c1), true)
  }
#undef PHASE
#undef LOADB

  // epilogue: C/D frag col = lane&15 (N side), row = (lane>>4)*4 + r (M side)
  const int rg = (lane >> 4) * 4;
  #pragma unroll
  for (int ni = 0; ni < 4; ++ni) {
    const int gn = n0 + wn * 64 + ni * 16 + fr;
    const float bvl = bias[gn];
    #pragma unroll
    for (int mi = 0; mi < 8; ++mi) {
      const int gmB = m0 + wm * 128 + mi * 16 + rg;
      f32x4 v = acc[mi][ni];
      if (OM == 0) {
        float* Cf = (float*)Cp;
        #pragma unroll
        for (int r = 0; r < 4; ++r)
          Cf[(long)(gmB + r) * LDC + gn] = v[r] + bvl;
      } else { // OM == 1: vT[((b*8+h)*256 + i)*256 + s]
        const int b = gmB >> 8, s = gmB & 255, h = gn >> 8, ii = gn & 255;
        u16x4 o;
        #pragma unroll
        for (int r = 0; r < 4; ++r) o[r] = f2bf(v[r] + bvl);
        *(u16x4*)&((unsigned short*)Cp)[((long)((b * 8 + h) * 256 + ii) << 8) + s] = o;
      }
    }
  }
}

// ---------------- 128x128 NT GEMM (m97 structure) — aggregation ----------------
template<int MODE, int OM, bool BATCHED>
__global__ __launch_bounds__(256)
void fgemm(const unsigned short* __restrict__ A, const unsigned short* __restrict__ B,
           const float* __restrict__ bias, void* __restrict__ C,
           int lda, int ldb, int ldc, int KT)
{
  __shared__ __align__(16) unsigned short lA[2 * 128 * 32];
  __shared__ __align__(16) unsigned short lB[2 * 128 * 32];

  const int tid  = threadIdx.x;
  const int lane = tid & 63;
  const int wid  = tid >> 6;
  const int wr   = wid >> 1;
  const int wc   = wid & 1;

  const int z  = BATCHED ? blockIdx.z : 0;
  const int m0 = blockIdx.y * 128;
  const int n0 = blockIdx.x * 128;

  long aBase = (long)m0 * lda;
  long bBase = (long)n0 * ldb;
  if (BATCHED) {
    aBase += (long)z * 256 * lda;
    bBase += (long)z * 256 * ldb;
  }

  const int ar0 = tid >> 2, ac0 = (tid & 3) * 8;
  const int ar1 = ar0 + 64, ac1 = ac0;

  const unsigned short* pa0 = A + aBase + (long)ar0 * lda + ac0;
  const unsigned short* pa1 = A + aBase + (long)ar1 * lda + ac1;
  const unsigned short* pb0 = B + bBase + (long)ar0 * ldb + ac0;
  const unsigned short* pb1 = B + bBase + (long)ar1 * ldb + ac1;

  constexpr int SUBOFF = (MODE == 0) ? 2048 : 32;
  constexpr int KSTEP  = (MODE == 0) ? 32 : 64;

  f32x4 acc[4][4];
  #pragma unroll
  for (int i = 0; i < 4; ++i)
    #pragma unroll
    for (int j = 0; j < 4; ++j)
      acc[i][j] = (f32x4)(0.0f);

  const int fr   = lane & 15;
  const int krow = (lane >> 4) * 8;

  for (int kt = 0; kt < KT; kt += KSTEP) {
    gload16(pa0 + kt,          lA + tid * 8);
    gload16(pa1 + kt,          lA + (tid + 256) * 8);
    gload16(pa0 + kt + SUBOFF, lA + 4096 + tid * 8);
    gload16(pa1 + kt + SUBOFF, lA + 4096 + (tid + 256) * 8);
    gload16(pb0 + kt,          lB + tid * 8);
    gload16(pb1 + kt,          lB + (tid + 256) * 8);
    gload16(pb0 + kt + SUBOFF, lB + 4096 + tid * 8);
    gload16(pb1 + kt + SUBOFF, lB + 4096 + (tid + 256) * 8);
    __syncthreads();

    s16x8 a0[4], a1[4], b0[4], b1[4];
    #pragma unroll
    for (int i = 0; i < 4; ++i) {
      const int r = (wr * 64 + i * 16 + fr) * 32 + krow;
      a0[i] = *(const s16x8*)&lA[r];
      a1[i] = *(const s16x8*)&lA[4096 + r];
    }
    #pragma unroll
    for (int j = 0; j < 4; ++j) {
      const int r = (wc * 64 + j * 16 + fr) * 32 + krow;
      b0[j] = *(const s16x8*)&lB[r];
      b1[j] = *(const s16x8*)&lB[4096 + r];
    }

    #pragma unroll
    for (int i = 0; i < 4; ++i)
      #pragma unroll
      for (int j = 0; j < 4; ++j) {
        if (MODE == 0) {
          acc[i][j] = __builtin_amdgcn_mfma_f32_16x16x32_bf16(a1[i], b0[j], acc[i][j], 0, 0, 0);
          acc[i][j] = __builtin_amdgcn_mfma_f32_16x16x32_bf16(a0[i], b1[j], acc[i][j], 0, 0, 0);
          acc[i][j] = __builtin_amdgcn_mfma_f32_16x16x32_bf16(a0[i], b0[j], acc[i][j], 0, 0, 0);
        } else {
          acc[i][j] = __builtin_amdgcn_mfma_f32_16x16x32_bf16(a0[i], b0[j], acc[i][j], 0, 0, 0);
          acc[i][j] = __builtin_amdgcn_mfma_f32_16x16x32_bf16(a1[i], b1[j], acc[i][j], 0, 0, 0);
        }
      }

    __syncthreads();
  }

  const int rg = (lane >> 4) * 4;
  #pragma unroll
  for (int j = 0; j < 4; ++j) {
    const int gn = n0 + wc * 64 + j * 16 + fr;
    const float bvl = bias ? bias[gn] : 0.0f;
    #pragma unroll
    for (int i = 0; i < 4; ++i) {
      const int gmB = m0 + wr * 64 + i * 16 + rg;
      f32x4 v = acc[i][j];
      if (OM == 0) {
        float* Cf = (float*)C;
        #pragma unroll
        for (int r = 0; r < 4; ++r)
          Cf[(long)(gmB + r) * ldc + gn] = v[r] + bvl;
      } else if (OM == 2) {
        long cb = 0;
        if (BATCHED) cb = (long)(z >> 3) * 256 * ldc + (long)(z & 7) * 256;
        unsigned short* Ch = (unsigned short*)C;
        #pragma unroll
        for (int r = 0; r < 4; ++r)
          Ch[cb + (long)(gmB + r) * ldc + gn] = f2bf(v[r] + bvl);
      } else {
        const int b = gmB >> 8, s = gmB & 255, h = gn >> 8, ii = gn & 255;
        u16x4 o;
        #pragma unroll
        for (int r = 0; r < 4; ++r) o[r] = f2bf(v[r] + bvl);
        *(u16x4*)&((unsigned short*)C)[((long)((b * 8 + h) * 256 + ii) << 8) + s] = o;
      }
    }
  }
}

// ---------------- circular correlation + softmax ----------------
// one wave per (b,h,l) row; packed f32x2 accumulators (v_pk_fma_f32 target)
__global__ __launch_bounds__(256)
void corr_softmax(const float* __restrict__ qp, const float* __restrict__ kp0,
                  const float* __restrict__ kp1, const float* __restrict__ temp,
                  unsigned short* __restrict__ w)
{
  __shared__ float qs[4][520];
  __shared__ float ks[4][264];
  const int tid  = threadIdx.x;
  const int lane = tid & 63;
  const int wid  = tid >> 6;
  const int row  = blockIdx.x * 4 + wid;       // ((b*8+h)*256+l)
  const int b = row >> 11;
  const int h = (row >> 8) & 7;
  const int l = row & 255;
  const long qbase = ((long)(b * 256 + l) << 11) + h * 256;
  const float* kb  = (b < 16) ? kp0 : kp1;
  const long kbase = ((long)((b & 15) * 256 + l) << 11) + h * 256;

  {
    f32x4 qv = *(const f32x4*)(qp + qbase + 4 * lane);
    f32x4 kv = *(const f32x4*)(kb + kbase + 4 * lane);
    *(f32x4*)&qs[wid][4 * lane]       = qv;
    *(f32x4*)&qs[wid][256 + 4 * lane] = qv;
    *(f32x4*)&ks[wid][4 * lane]       = kv;
  }
  __syncthreads();

  f32x2 c01 = (f32x2)(0.0f), c23 = (f32x2)(0.0f);
  const int d = 4 * lane;
  const float* Q  = &qs[wid][0];
  const float* Kv = &ks[wid][0];
  #pragma unroll 4
  for (int u0 = 0; u0 < 256; u0 += 4) {
    f32x4 K4 = *(const f32x4*)(Kv + u0);
    f32x4 Qa = *(const f32x4*)(Q + u0 + d);
    f32x4 Qb = *(const f32x4*)(Q + u0 + d + 4);
    f32x2 q01 = (f32x2){Qa[0], Qa[1]};
    f32x2 q12 = (f32x2){Qa[1], Qa[2]};
    f32x2 q23 = (f32x2){Qa[2], Qa[3]};
    f32x2 q30 = (f32x2){Qa[3], Qb[0]};
    f32x2 q45 = (f32x2){Qb[0], Qb[1]};
    f32x2 q56 = (f32x2){Qb[1], Qb[2]};
    c01 += K4[0] * q01; c01 += K4[1] * q12; c01 += K4[2] * q23; c01 += K4[3] * q30;
    c23 += K4[0] * q23; c23 += K4[1] * q30; c23 += K4[2] * q45; c23 += K4[3] * q56;
  }
  float c0 = c01[0], c1 = c01[1], c2 = c23[0], c3 = c23[1];

  const float invT = 1.0f / temp[h];
  float mx = fmaxf(fmaxf(c0, c1), fmaxf(c2, c3));
  #pragma unroll
  for (int off = 32; off >= 1; off >>= 1) mx = fmaxf(mx, __shfl_xor(mx, off, 64));
  const float e0 = __expf((c0 - mx) * invT);
  const float e1 = __expf((c1 - mx) * invT);
  const float e2 = __expf((c2 - mx) * invT);
  const float e3 = __expf((c3 - mx) * invT);
  float sm = e0 + e1 + e2 + e3;
  #pragma unroll
  for (int off = 32; off >= 1; off >>= 1) sm += __shfl_xor(sm, off, 64);
  const float rs = 1.0f / sm;
  u16x4 o;
  o[0] = f2bf(e0 * rs); o[1] = f2bf(e1 * rs); o[2] = f2bf(e2 * rs); o[3] = f2bf(e3 * rs);
  *(u16x4*)(w + (long)row * 256 + d) = o;
}

// ---------------- launcher ----------------

extern "C" void kernel_launch(void* const* d_in, const int* in_sizes, int n_in,
                              void* d_out, int out_size, void* d_ws, size_t ws_size,
                              hipStream_t stream) {
  (void)in_sizes; (void)n_in; (void)out_size; (void)ws_size;
  const float* queries = (const float*)d_in[0];
  const float* keys    = (const float*)d_in[1];
  const float* values  = (const float*)d_in[2];
  const float* Wq = (const float*)d_in[3];
  const float* bq = (const float*)d_in[4];
  const float* Wk = (const float*)d_in[5];
  const float* bk = (const float*)d_in[6];
  const float* Wv = (const float*)d_in[7];
  const float* bv = (const float*)d_in[8];
  const float* Wo = (const float*)d_in[9];
  const float* bo = (const float*)d_in[10];
  const float* temp = (const float*)d_in[11];

  // workspace (peak 192 MiB) + d_out as W-pack scratch:
  //  ws[0,32)    extA f16 (queries, then keys) -> wgt bf16 after K-GEMM
  //  ws[32,96)   qproj fp32 -> vT[32,64) + out2[64,96) after corr
  //  ws[96,160)  kproj fp32 -> Wob[96,104) after corr
  //  ws[160,192) Vb bf16 (values)
  //  d_out       extW (packed W, <=8 MiB) until the final GEMM
  char* ws = (char*)d_ws;
  auto MB = [](size_t m) { return m << 20; };
  unsigned short* extA = (unsigned short*)ws;
  unsigned short* wgt  = (unsigned short*)ws;
  float*          qproj= (float*)(ws + MB(32));
  unsigned short* vT   = (unsigned short*)(ws + MB(32));
  unsigned short* out2 = (unsigned short*)(ws + MB(64));
  float*          kproj= (float*)(ws + MB(96));
  unsigned short* Wob  = (unsigned short*)(ws + MB(96));
  unsigned short* Vb   = (unsigned short*)(ws + MB(160));
  unsigned short* extW = (unsigned short*)d_out;

  dim3 blk(256);
  dim3 gBig(32, 8);   // 256 blocks; bx -> M (XCD-remapped in-kernel), by -> N

  // ---- Q projection (fp16 single-pass) ----
  pack_f16<<<2048, blk, 0, stream>>>(queries, extA, (long)8192 * 2048 / 8);
  pack_f16<<<2048, blk, 0, stream>>>(Wq, extW, (long)2048 * 2048 / 8);
  gemm8p<1, 0><<<gBig, 512, 0, stream>>>(extA, extW, bq, qproj);
  // ---- K projection (fp16 single-pass) ----
  pack_f16<<<2048, blk, 0, stream>>>(keys, extA, (long)8192 * 2048 / 8);
  pack_f16<<<2048, blk, 0, stream>>>(Wk, extW, (long)2048 * 2048 / 8);
  gemm8p<1, 0><<<gBig, 512, 0, stream>>>(extA, extW, bk, kproj);
  // ---- correlation + softmax -> bf16 weights ----
  corr_softmax<<<dim3(16384), blk, 0, stream>>>(qproj, kproj,
                                                kproj + (long)16 * 256 * 2048, temp, wgt);
  // ---- V projection (bf16), epilogue scatters transposed vT[b,h,i,s] ----
  pack_bf16<<<2048, blk, 0, stream>>>(values, Vb, (long)8192 * 2048 / 8);
  pack_bf16<<<2048, blk, 0, stream>>>(Wv, extW, (long)2048 * 2048 / 8);
  gemm8p<0, 1><<<gBig, 512, 0, stream>>>(Vb, extW, bv, vT);
  // ---- aggregation: out2[b*256+l][h*256+i] = sum_s wgt[bhl][s]*vT[bhi][s] ----
  fgemm<1, 2, true><<<dim3(2, 2, 256), blk, 0, stream>>>(wgt, vT, nullptr, out2,
                                                         256, 256, 2048, 256);
  // ---- O projection -> d_out (fp32) ----
  pack_bf16<<<2048, blk, 0, stream>>>(Wo, Wob, (long)2048 * 2048 / 8);
  gemm8p<0, 0><<<gBig, 512, 0, stream>>>(out2, Wob, bo, (float*)d_out);
}